// Round 1
// baseline (734.849 us; speedup 1.0000x reference)
//
#include <hip/hip_runtime.h>
#include <hip/hip_bf16.h>
#include <math.h>

typedef __attribute__((ext_vector_type(8))) short bf16x8;
typedef __attribute__((ext_vector_type(4))) float f32x4;

__device__ __forceinline__ float b2f(unsigned short u) {
    unsigned int v = ((unsigned int)u) << 16;
    return __uint_as_float(v);
}
__device__ __forceinline__ unsigned short f2b(float f) {
    __hip_bfloat16 h = __float2bfloat16(f);
    return *reinterpret_cast<unsigned short*>(&h);
}
// truncation split: hi = top 16 bits, lo = RNE(v - hi). residual ~2^-17 |v|
__device__ __forceinline__ void split_trunc(float v, short& h, short& l) {
    unsigned int ui = __float_as_uint(v);
    h = (short)(ui >> 16);
    float hf = __uint_as_float(ui & 0xffff0000u);
    l = (short)f2b(v - hf);
}

// ============ prep: conv + w3 weights ============
__global__ __launch_bounds__(256) void prep_w(
    const float* __restrict__ w1, const float* __restrict__ w2, const float* __restrict__ w3,
    const float* __restrict__ ew3,
    unsigned short* __restrict__ wb1h, unsigned short* __restrict__ wb1l,
    unsigned short* __restrict__ w2h, unsigned short* __restrict__ w2l,
    unsigned short* __restrict__ w3h, unsigned short* __restrict__ w3l,
    float* __restrict__ w3t) {
    int tid = blockIdx.x * 256 + threadIdx.x;
    if (tid < 8192) {
        int k = tid >> 8, r = tid & 255;
        int c = r >> 6, ky = (r >> 3) & 7, kx = r & 7;
        float v = w1[tid];
        unsigned short h = f2b(v);
        int d = ((ky * 2 + (k >> 4)) * 16 + (k & 15)) * 32 + c * 8 + kx;
        wb1h[d] = h;
        wb1l[d] = f2b(v - b2f(h));
    } else if (tid < 8192 + 32768) {
        int i = tid - 8192;
        int n = i >> 9, r = i & 511;
        int c = r >> 4, ky = (r >> 2) & 3, kx = r & 3;
        float v = w2[i];
        unsigned short h = f2b(v);
        int d = ((ky * 4 + kx) * 64 + n) * 32 + c;
        w2h[d] = h;
        w2l[d] = f2b(v - b2f(h));
    } else if (tid < 8192 + 32768 + 36864) {
        int i = tid - 40960;
        int n = i / 576, r = i - n * 576;
        int c = r / 9, s = r - c * 9;
        int ky = s / 3, kx = s - ky * 3;
        float v = w3[i];
        unsigned short h = f2b(v);
        int d = (((ky * 3 + kx) * 2 + (c >> 5)) * 64 + n) * 32 + (c & 31);
        w3h[d] = h;
        w3l[d] = f2b(v - b2f(h));
    } else if (tid < 77824 + 36864) {
        int i = tid - 77824;
        int e = i / 6144, rem = i - e * 6144;
        int a = rem >> 9, k = rem & 511;
        w3t[i] = ew3[e * 6144 + k * 12 + a];
    }
}

// ============ prep: fc weights: fc_w[(c*49+p)*512+n] -> fcw[n][(p*64+c)] hi/lo ============
__global__ __launch_bounds__(256) void prep_fcw(
    const float* __restrict__ fw, unsigned short* __restrict__ h, unsigned short* __restrict__ l) {
    __shared__ float tile[64][65];
    int k0 = blockIdx.x * 64;
    int n0 = blockIdx.y * 64;
    int tx = threadIdx.x & 63, ty = threadIdx.x >> 6;
#pragma unroll
    for (int j = 0; j < 16; j++) {
        int kk = ty + j * 4;
        int kp = k0 + kk;
        int p = kp >> 6, c = kp & 63;
        tile[kk][tx] = fw[(c * 49 + p) * 512 + n0 + tx];
    }
    __syncthreads();
#pragma unroll
    for (int j = 0; j < 16; j++) {
        int r = ty + j * 4;
        float v = tile[tx][r];
        unsigned short hh = f2b(v);
        long d = (long)(n0 + r) * 3136 + k0 + tx;
        h[d] = hh;
        l[d] = f2b(v - b2f(hh));
    }
}

// ============ prep: expert weights [e][d][h] -> bf16 [e][h][d] ============
__global__ __launch_bounds__(256) void prep_ewT(
    const float* __restrict__ ew1, const float* __restrict__ ew2,
    unsigned short* __restrict__ t1, unsigned short* __restrict__ t2) {
    __shared__ float tile[32][33];
    int z = blockIdx.z;
    int e = z % 6;
    const float* src = (z < 6) ? (ew1 + e * 262144) : (ew2 + e * 262144);
    unsigned short* dst = (z < 6) ? (t1 + e * 262144) : (t2 + e * 262144);
    int d0 = blockIdx.y * 32;
    int h0 = blockIdx.x * 32;
    int tx = threadIdx.x, ty = threadIdx.y;
#pragma unroll
    for (int j = 0; j < 4; j++)
        tile[ty + j * 8][tx] = src[(d0 + ty + j * 8) * 512 + h0 + tx];
    __syncthreads();
#pragma unroll
    for (int j = 0; j < 4; j++)
        dst[(h0 + ty + j * 8) * 512 + (d0 + tx)] = f2b(tile[tx][ty + j * 8]);
}

// ============ conv1: direct MFMA. Weights staged in LDS so the MFMA wait is
// lgkmcnt-only — the per-ky x prefetch stays in flight on vmcnt across
// iterations instead of being drained by a weight-load vmcnt(0). ============
__global__ __launch_bounds__(256, 3) void conv1_k(
    const float* __restrict__ x, const unsigned short* __restrict__ wbh,
    const unsigned short* __restrict__ wbl, const float* __restrict__ b1,
    unsigned short* __restrict__ yhi, unsigned short* __restrict__ ylo) {
    // [ky][table][lane] fragment-major: ds_read_b128 at lane*16 -> conflict-free
    __shared__ bf16x8 wlds[8][4][64];
    int t = threadIdx.x;
    {
        int tab = t >> 6, ln = t & 63;
        const unsigned short* sb = ((tab < 2) ? wbh : wbl) +
            ((ln & 15) * 32 + (ln >> 4) * 8 + (tab & 1) * 512);
#pragma unroll
        for (int k = 0; k < 8; k++)
            wlds[k][tab][ln] = *(const bf16x8*)(sb + k * 1024);
    }
    int wave = t >> 6, lane = t & 63, l16 = lane & 15, quad = lane >> 4;
    int px0 = blockIdx.x * 256 + wave * 64;
    const float* abase[4];
#pragma unroll
    for (int i = 0; i < 4; i++) {
        int px = px0 + i * 16 + l16;
        int n = px / 400;
        int rem = px - n * 400;
        int oy = rem / 20;
        int ox = rem - oy * 20;
        abase[i] = x + (long)n * 28224 + quad * 7056 + oy * 4 * 84 + ox * 4;
    }
    f32x4 acc[4][2];
#pragma unroll
    for (int i = 0; i < 4; i++)
#pragma unroll
        for (int j = 0; j < 2; j++)
#pragma unroll
            for (int r = 0; r < 4; r++) acc[i][j][r] = 0.f;
    __syncthreads();
    float4 cur[8];
#pragma unroll
    for (int i = 0; i < 4; i++) {
        cur[i * 2] = *(const float4*)abase[i];
        cur[i * 2 + 1] = *(const float4*)(abase[i] + 4);
    }
#pragma unroll
    for (int ky = 0; ky < 8; ky++) {
        float4 nxt[8];
        if (ky < 7) {
#pragma unroll
            for (int i = 0; i < 4; i++) {
                const float* p = abase[i] + (ky + 1) * 84;
                nxt[i * 2] = *(const float4*)p;
                nxt[i * 2 + 1] = *(const float4*)(p + 4);
            }
        }
        bf16x8 bh0 = wlds[ky][0][lane];
        bf16x8 bh1 = wlds[ky][1][lane];
        bf16x8 bl0 = wlds[ky][2][lane];
        bf16x8 bl1 = wlds[ky][3][lane];
        bf16x8 ah[4], al[4];
#pragma unroll
        for (int i = 0; i < 4; i++) {
            float v[8] = {cur[i * 2].x, cur[i * 2].y, cur[i * 2].z, cur[i * 2].w,
                          cur[i * 2 + 1].x, cur[i * 2 + 1].y, cur[i * 2 + 1].z, cur[i * 2 + 1].w};
#pragma unroll
            for (int j = 0; j < 8; j++) {
                short hh, ll;
                split_trunc(v[j], hh, ll);
                ah[i][j] = hh;
                al[i][j] = ll;
            }
        }
#pragma unroll
        for (int i = 0; i < 4; i++) {
            acc[i][0] = __builtin_amdgcn_mfma_f32_16x16x32_bf16(ah[i], bh0, acc[i][0], 0, 0, 0);
            acc[i][0] = __builtin_amdgcn_mfma_f32_16x16x32_bf16(al[i], bh0, acc[i][0], 0, 0, 0);
            acc[i][0] = __builtin_amdgcn_mfma_f32_16x16x32_bf16(ah[i], bl0, acc[i][0], 0, 0, 0);
            acc[i][1] = __builtin_amdgcn_mfma_f32_16x16x32_bf16(ah[i], bh1, acc[i][1], 0, 0, 0);
            acc[i][1] = __builtin_amdgcn_mfma_f32_16x16x32_bf16(al[i], bh1, acc[i][1], 0, 0, 0);
            acc[i][1] = __builtin_amdgcn_mfma_f32_16x16x32_bf16(ah[i], bl1, acc[i][1], 0, 0, 0);
        }
        if (ky < 7) {
#pragma unroll
            for (int q = 0; q < 8; q++) cur[q] = nxt[q];
        }
    }
    float bias0 = b1[l16], bias1 = b1[16 + l16];
#pragma unroll
    for (int i = 0; i < 4; i++) {
#pragma unroll
        for (int r = 0; r < 4; r++) {
            long px = px0 + i * 16 + quad * 4 + r;
            long o = px * 32;
            float v0 = fmaxf(acc[i][0][r] + bias0, 0.f);
            float v1 = fmaxf(acc[i][1][r] + bias1, 0.f);
            short h0, l0, h1, l1;
            split_trunc(v0, h0, l0);
            split_trunc(v1, h1, l1);
            yhi[o + l16] = (unsigned short)h0;
            ylo[o + l16] = (unsigned short)l0;
            yhi[o + 16 + l16] = (unsigned short)h1;
            ylo[o + 16 + l16] = (unsigned short)l1;
        }
    }
}

// ============ conv2/3: LDS-free implicit-GEMM, 1 wave per block, 64px x 64ch ============
template <int C, int IH, int IW, int OH, int OW, int S, int KH, int KW>
__global__ __launch_bounds__(64, 3) void convm_k(
    const unsigned short* __restrict__ xhi, const unsigned short* __restrict__ xlo,
    const unsigned short* __restrict__ whi, const unsigned short* __restrict__ wlo,
    const float* __restrict__ bias,
    unsigned short* __restrict__ yhi, unsigned short* __restrict__ ylo) {
    constexpr int CH = C / 32;
    constexpr int NCHUNK = KH * KW * CH;
    int lane = threadIdx.x, l16 = lane & 15, quad = lane >> 4;
    int pxbase = blockIdx.x * 64;
    long xoff[4];
#pragma unroll
    for (int i = 0; i < 4; i++) {
        int px = pxbase + i * 16 + l16;
        int n = px / (OH * OW);
        int rem = px - n * (OH * OW);
        int oy = rem / OW;
        int ox = rem - oy * OW;
        xoff[i] = (((long)n * IH + oy * S) * IW + ox * S) * C + quad * 8;
    }
    f32x4 acc[4][4];
#pragma unroll
    for (int i = 0; i < 4; i++)
#pragma unroll
        for (int j = 0; j < 4; j++)
#pragma unroll
            for (int r = 0; r < 4; r++) acc[i][j][r] = 0.f;
#pragma unroll 2
    for (int ck = 0; ck < NCHUNK; ck++) {
        int kyx = ck / CH;
        int ch = ck - kyx * CH;
        int ky = kyx / KW, kx = kyx - ky * KW;
        long koff = ((long)(ky * IW + kx)) * C + ch * 32;
        bf16x8 ah[4], al[4], bh[4], bl[4];
#pragma unroll
        for (int i = 0; i < 4; i++) {
            ah[i] = *(const bf16x8*)(xhi + xoff[i] + koff);
            al[i] = *(const bf16x8*)(xlo + xoff[i] + koff);
        }
#pragma unroll
        for (int j = 0; j < 4; j++) {
            long b = ((long)ck * 64 + j * 16 + l16) * 32 + quad * 8;
            bh[j] = *(const bf16x8*)(whi + b);
            bl[j] = *(const bf16x8*)(wlo + b);
        }
#pragma unroll
        for (int i = 0; i < 4; i++)
#pragma unroll
            for (int j = 0; j < 4; j++) {
                acc[i][j] = __builtin_amdgcn_mfma_f32_16x16x32_bf16(ah[i], bh[j], acc[i][j], 0, 0, 0);
                acc[i][j] = __builtin_amdgcn_mfma_f32_16x16x32_bf16(ah[i], bl[j], acc[i][j], 0, 0, 0);
                acc[i][j] = __builtin_amdgcn_mfma_f32_16x16x32_bf16(al[i], bh[j], acc[i][j], 0, 0, 0);
            }
    }
#pragma unroll
    for (int i = 0; i < 4; i++)
#pragma unroll
        for (int j = 0; j < 4; j++) {
            int col = j * 16 + l16;
            float bv = bias[col];
#pragma unroll
            for (int r = 0; r < 4; r++) {
                int prow = pxbase + i * 16 + quad * 4 + r;
                float v = fmaxf(acc[i][j][r] + bv, 0.f);
                unsigned short h = f2b(v);
                yhi[(long)prow * 64 + col] = h;
                ylo[(long)prow * 64 + col] = f2b(v - b2f(h));
            }
        }
}

// ============ fc: LDS-free split-bf16 MFMA, 1 wave per block, K-split x7 ============
__global__ __launch_bounds__(64, 3) void fc_k(
    const unsigned short* __restrict__ Ahi, const unsigned short* __restrict__ Alo,
    const unsigned short* __restrict__ Bhi, const unsigned short* __restrict__ Blo,
    float* __restrict__ Cp) {
    int lane = threadIdx.x, l16 = lane & 15, quad = lane >> 4;
    int m0 = blockIdx.x * 64, n0 = blockIdx.y * 64;
    int z = blockIdx.z;
    int kBase = z * 448;
    f32x4 acc[4][4];
#pragma unroll
    for (int i = 0; i < 4; i++)
#pragma unroll
        for (int j = 0; j < 4; j++)
#pragma unroll
            for (int r = 0; r < 4; r++) acc[i][j][r] = 0.f;
#pragma unroll 2
    for (int k0 = kBase; k0 < kBase + 448; k0 += 32) {
        bf16x8 ah[4], al[4], bh[4], bl[4];
#pragma unroll
        for (int i = 0; i < 4; i++) {
            long a = (long)(m0 + i * 16 + l16) * 3136 + k0 + quad * 8;
            ah[i] = *(const bf16x8*)(Ahi + a);
            al[i] = *(const bf16x8*)(Alo + a);
        }
#pragma unroll
        for (int j = 0; j < 4; j++) {
            long b = (long)(n0 + j * 16 + l16) * 3136 + k0 + quad * 8;
            bh[j] = *(const bf16x8*)(Bhi + b);
            bl[j] = *(const bf16x8*)(Blo + b);
        }
#pragma unroll
        for (int i = 0; i < 4; i++)
#pragma unroll
            for (int j = 0; j < 4; j++) {
                acc[i][j] = __builtin_amdgcn_mfma_f32_16x16x32_bf16(ah[i], bh[j], acc[i][j], 0, 0, 0);
                acc[i][j] = __builtin_amdgcn_mfma_f32_16x16x32_bf16(ah[i], bl[j], acc[i][j], 0, 0, 0);
                acc[i][j] = __builtin_amdgcn_mfma_f32_16x16x32_bf16(al[i], bh[j], acc[i][j], 0, 0, 0);
            }
    }
    float* Cz = Cp + (long)z * 1048576;
#pragma unroll
    for (int i = 0; i < 4; i++)
#pragma unroll
        for (int j = 0; j < 4; j++) {
            int col = n0 + j * 16 + l16;
#pragma unroll
            for (int r = 0; r < 4; r++) {
                int row = m0 + i * 16 + quad * 4 + r;
                Cz[row * 512 + col] = acc[i][j][r];
            }
        }
}

// ============ fc finalize: sum 7 partials + bias + relu; also zero moe counters ============
__global__ __launch_bounds__(256) void fc_fin(
    const float* __restrict__ Cp, const float* __restrict__ bias,
    float* __restrict__ f, unsigned short* __restrict__ fb, int* __restrict__ cnt) {
    if (blockIdx.x == 0 && threadIdx.x < 8) cnt[threadIdx.x] = 0;
    int tid = blockIdx.x * 256 + threadIdx.x;
    int col = tid & 511;
    float v = bias[col];
#pragma unroll
    for (int z = 0; z < 7; z++) v += Cp[tid + (long)z * 1048576];
    v = fmaxf(v, 0.f);
    f[tid] = v;
    fb[tid] = f2b(v);
}

// ============ gate: top-2 + expert-row compaction ============
__global__ __launch_bounds__(256) void gate_k(
    const float* __restrict__ f, const float* __restrict__ gw, const float* __restrict__ gb,
    int* __restrict__ topi, float* __restrict__ topp,
    int* __restrict__ cnt, int* __restrict__ rowlist, int* __restrict__ slotp) {
    int wave = threadIdx.x >> 6, lane = threadIdx.x & 63;
    int row = blockIdx.x * 4 + wave;
    float fv[8];
#pragma unroll
    for (int j = 0; j < 8; j++) fv[j] = f[row * 512 + lane + 64 * j];
    float lg[6];
#pragma unroll
    for (int e = 0; e < 6; e++) {
        float a = 0.f;
#pragma unroll
        for (int j = 0; j < 8; j++) a += fv[j] * gw[(lane + 64 * j) * 6 + e];
#pragma unroll
        for (int off = 32; off > 0; off >>= 1) a += __shfl_xor(a, off, 64);
        lg[e] = a + gb[e];
    }
    if (lane == 0) {
        int i1 = 0;
        float v1 = lg[0];
#pragma unroll
        for (int e = 1; e < 6; e++)
            if (lg[e] > v1) { v1 = lg[e]; i1 = e; }
        int i2 = (i1 == 0) ? 1 : 0;
        float v2 = lg[i2];
#pragma unroll
        for (int e = 0; e < 6; e++)
            if (e != i1 && lg[e] > v2) { v2 = lg[e]; i2 = e; }
        float pa = 1.f / (1.f + expf(v2 - v1));
        topi[row * 2] = i1;
        topi[row * 2 + 1] = i2;
        topp[row * 2] = pa;
        topp[row * 2 + 1] = 1.f - pa;
        int s1 = atomicAdd(cnt + i1, 1);
        int s2 = atomicAdd(cnt + i2, 1);
        rowlist[i1 * 2048 + s1] = row;
        rowlist[i2 * 2048 + s2] = row;
        slotp[row * 2] = s1;
        slotp[row * 2 + 1] = s2;
    }
}

// ============ expert GEMM: compacted rows; gather A when rowlist != null ============
__global__ __launch_bounds__(64, 4) void moe_gemm(
    const unsigned short* __restrict__ A, long aStride,
    const unsigned short* __restrict__ Bt, const float* __restrict__ bias,
    unsigned short* __restrict__ C,
    const int* __restrict__ cnt, const int* __restrict__ rowlist) {
    int e = blockIdx.z;
    int ne = cnt[e];
    int m0 = blockIdx.x * 64;
    if (m0 >= ne) return;
    const unsigned short* Ae = A + (long)e * aStride;
    const unsigned short* Be = Bt + (long)e * 262144;
    const float* be = bias + e * 512;
    unsigned short* Ce = C + (long)e * 2048 * 512;
    int lane = threadIdx.x, l16 = lane & 15, quad = lane >> 4;
    int n0 = blockIdx.y * 64;
    int arow[4];
#pragma unroll
    for (int i = 0; i < 4; i++) {
        int slot = m0 + i * 16 + l16;
        arow[i] = rowlist ? ((slot < ne) ? rowlist[e * 2048 + slot] : 0) : slot;
    }
    f32x4 acc[4][4];
#pragma unroll
    for (int i = 0; i < 4; i++)
#pragma unroll
        for (int j = 0; j < 4; j++)
#pragma unroll
            for (int r = 0; r < 4; r++) acc[i][j][r] = 0.f;
#pragma unroll 4
    for (int k0 = 0; k0 < 512; k0 += 32) {
        bf16x8 a[4], b[4];
#pragma unroll
        for (int i = 0; i < 4; i++)
            a[i] = *(const bf16x8*)(Ae + (long)arow[i] * 512 + k0 + quad * 8);
#pragma unroll
        for (int j = 0; j < 4; j++)
            b[j] = *(const bf16x8*)(Be + (long)(n0 + j * 16 + l16) * 512 + k0 + quad * 8);
#pragma unroll
        for (int i = 0; i < 4; i++)
#pragma unroll
            for (int j = 0; j < 4; j++)
                acc[i][j] = __builtin_amdgcn_mfma_f32_16x16x32_bf16(a[i], b[j], acc[i][j], 0, 0, 0);
    }
#pragma unroll
    for (int i = 0; i < 4; i++)
#pragma unroll
        for (int j = 0; j < 4; j++) {
            int col = n0 + j * 16 + l16;
            float bcol = be[col];
#pragma unroll
            for (int r = 0; r < 4; r++) {
                int row = m0 + i * 16 + quad * 4 + r;
                float v = fmaxf(acc[i][j][r] + bcol, 0.f);
                Ce[(long)row * 512 + col] = f2b(v);
            }
        }
}

// ============ combine: wave per row, coalesced, shuffle-reduce ============
__global__ __launch_bounds__(256) void combine_k(
    const unsigned short* __restrict__ h2, const float* __restrict__ w3t,
    const float* __restrict__ b3, const int* __restrict__ topi,
    const float* __restrict__ topp, const int* __restrict__ slotp,
    float* __restrict__ out) {
    int b = blockIdx.x * 4 + (threadIdx.x >> 6);
    int lane = threadIdx.x & 63;
    int e0 = topi[b * 2], e1 = topi[b * 2 + 1];
    float p0 = topp[b * 2], p1 = topp[b * 2 + 1];
    int s0 = slotp[b * 2], s1 = slotp[b * 2 + 1];
    float r[12];
#pragma unroll
    for (int a = 0; a < 12; a++) r[a] = 0.f;
#pragma unroll
    for (int j = 0; j < 2; j++) {
        int e = j ? e1 : e0;
        int s = j ? s1 : s0;
        float p = j ? p1 : p0;
        const unsigned short* hp = h2 + ((long)e * 2048 + s) * 512 + lane * 8;
        bf16x8 hv = *(const bf16x8*)hp;
        float hf[8];
#pragma unroll
        for (int q = 0; q < 8; q++) hf[q] = b2f((unsigned short)hv[q]);
        const float* wb = w3t + e * 6144 + lane * 8;
#pragma unroll
        for (int a = 0; a < 12; a++) {
            float4 w0 = *(const float4*)(wb + a * 512);
            float4 w1 = *(const float4*)(wb + a * 512 + 4);
            float acc = hf[0] * w0.x + hf[1] * w0.y + hf[2] * w0.z + hf[3] * w0.w +
                        hf[4] * w1.x + hf[5] * w1.y + hf[6] * w1.z + hf[7] * w1.w;
            r[a] += p * acc;
        }
    }
#pragma unroll
    for (int a = 0; a < 12; a++)
#pragma unroll
        for (int off = 32; off > 0; off >>= 1) r[a] += __shfl_xor(r[a], off, 64);
    float v = 0.f;
#pragma unroll
    for (int a = 0; a < 12; a++)
        if (lane == a) v = r[a];
    if (lane < 12)
        out[b * 12 + lane] = v + p0 * b3[e0 * 12 + lane] + p1 * b3[e1 * 12 + lane];
}

extern "C" void kernel_launch(void* const* d_in, const int* in_sizes, int n_in,
                              void* d_out, int out_size, void* d_ws, size_t ws_size,
                              hipStream_t stream) {
    const float* x   = (const float*)d_in[0];
    const float* c1w = (const float*)d_in[1];
    const float* c1b = (const float*)d_in[2];
    const float* c2w = (const float*)d_in[3];
    const float* c2b = (const float*)d_in[4];
    const float* c3w = (const float*)d_in[5];
    const float* c3b = (const float*)d_in[6];
    const float* fcw = (const float*)d_in[7];
    const float* fcb = (const float*)d_in[8];
    const float* gw  = (const float*)d_in[9];
    const float* gb  = (const float*)d_in[10];
    const float* ew1 = (const float*)d_in[11];
    const float* eb1 = (const float*)d_in[12];
    const float* ew2 = (const float*)d_in[13];
    const float* eb2 = (const float*)d_in[14];
    const float* ew3 = (const float*)d_in[15];
    const float* eb3 = (const float*)d_in[16];

    char* ws = (char*)d_ws;
    unsigned short* y1hi = (unsigned short*)(ws + 0L);          // 52428800 B
    unsigned short* y1lo = (unsigned short*)(ws + 52428800L);   // 52428800 B
    unsigned short* f3hi = (unsigned short*)(ws + 0L);          // alias (y1 dead after conv2)
    unsigned short* f3lo = (unsigned short*)(ws + 12845056L);   // alias
    // moe routing aux: inside [25690112, 52428800) — dead after conv2/conv3,
    // written only from fc_fin (zeroing) / gate onward.
    int*   cnt           = (int*)(ws + 26214400L);              // 32 B
    int*   rowlist       = (int*)(ws + 26214464L);              // 49152 B
    int*   slotp         = (int*)(ws + 26263616L);              // 16384 B
    unsigned short* y2hi = (unsigned short*)(ws + 104857600L);  // 21233664 B
    unsigned short* y2lo = (unsigned short*)(ws + 126091264L);  // 21233664 B
    unsigned short* h1   = (unsigned short*)(ws + 104857600L);  // alias (y2 dead after conv3)
    unsigned short* h2   = (unsigned short*)(ws + 117440512L);  // alias
    float* f             = (float*)(ws + 147324928L);           // 4194304 B
    unsigned short* fb   = (unsigned short*)(ws + 151519232L);  // 2097152 B
    int*   topi          = (int*)(ws + 153616384L);             // 16384 B
    float* topp          = (float*)(ws + 153632768L);           // 16384 B
    unsigned short* w2h  = (unsigned short*)(ws + 153681920L);  // 65536 B
    unsigned short* w2l  = (unsigned short*)(ws + 153747456L);  // 65536 B
    unsigned short* w3h  = (unsigned short*)(ws + 153812992L);  // 73728 B
    unsigned short* w3l  = (unsigned short*)(ws + 153886720L);  // 73728 B
    unsigned short* fcwh = (unsigned short*)(ws + 153960448L);  // 3211264 B
    unsigned short* fcwl = (unsigned short*)(ws + 157171712L);  // 3211264 B
    unsigned short* ew1t = (unsigned short*)(ws + 160382976L);  // 3145728 B
    unsigned short* ew2t = (unsigned short*)(ws + 163528704L);  // 3145728 B
    float* w3t           = (float*)(ws + 166674432L);           // 147456 B
    float* Cp            = (float*)(ws + 166821888L);           // 7*4194304 = 29360128 B
    unsigned short* wb1h = (unsigned short*)(ws + 196182016L);  // 16384 B
    unsigned short* wb1l = (unsigned short*)(ws + 196198400L);  // 16384 B (end 196214784)
    float* out = (float*)d_out;

    hipLaunchKernelGGL(prep_w, dim3(448), dim3(256), 0, stream, c1w, c2w, c3w, ew3,
                       wb1h, wb1l, w2h, w2l, w3h, w3l, w3t);
    hipLaunchKernelGGL(prep_fcw, dim3(49, 8), dim3(256), 0, stream, fcw, fcwh, fcwl);
    hipLaunchKernelGGL(prep_ewT, dim3(16, 16, 12), dim3(32, 8), 0, stream, ew1, ew2, ew1t, ew2t);
    hipLaunchKernelGGL(conv1_k, dim3(3200), dim3(256), 0, stream, x, wb1h, wb1l, c1b, y1hi, y1lo);
    hipLaunchKernelGGL((convm_k<32, 20, 20, 9, 9, 2, 4, 4>), dim3(2592), dim3(64), 0, stream,
                       y1hi, y1lo, w2h, w2l, c2b, y2hi, y2lo);
    hipLaunchKernelGGL((convm_k<64, 9, 9, 7, 7, 1, 3, 3>), dim3(1568), dim3(64), 0, stream,
                       y2hi, y2lo, w3h, w3l, c3b, f3hi, f3lo);
    hipLaunchKernelGGL(fc_k, dim3(32, 8, 7), dim3(64), 0, stream, f3hi, f3lo, fcwh, fcwl, Cp);
    hipLaunchKernelGGL(fc_fin, dim3(4096), dim3(256), 0, stream, Cp, fcb, f, fb, cnt);
    hipLaunchKernelGGL(gate_k, dim3(512), dim3(256), 0, stream, f, gw, gb, topi, topp,
                       cnt, rowlist, slotp);
    hipLaunchKernelGGL(moe_gemm, dim3(32, 8, 6), dim3(64), 0, stream, fb, 0L, ew1t, eb1, h1,
                       cnt, rowlist);
    hipLaunchKernelGGL(moe_gemm, dim3(32, 8, 6), dim3(64), 0, stream, h1, 1048576L, ew2t, eb2, h2,
                       cnt, (const int*)nullptr);
    hipLaunchKernelGGL(combine_k, dim3(512), dim3(256), 0, stream, h2, w3t, eb3, topi, topp,
                       slotp, out);
}

// Round 2
// 712.132 us; speedup vs baseline: 1.0319x; 1.0319x over previous
//
#include <hip/hip_runtime.h>
#include <hip/hip_bf16.h>
#include <math.h>

typedef __attribute__((ext_vector_type(8))) short bf16x8;
typedef __attribute__((ext_vector_type(4))) float f32x4;

__device__ __forceinline__ float b2f(unsigned short u) {
    unsigned int v = ((unsigned int)u) << 16;
    return __uint_as_float(v);
}
__device__ __forceinline__ unsigned short f2b(float f) {
    __hip_bfloat16 h = __float2bfloat16(f);
    return *reinterpret_cast<unsigned short*>(&h);
}
// truncation split: hi = top 16 bits, lo = RNE(v - hi). residual ~2^-17 |v|
__device__ __forceinline__ void split_trunc(float v, short& h, short& l) {
    unsigned int ui = __float_as_uint(v);
    h = (short)(ui >> 16);
    float hf = __uint_as_float(ui & 0xffff0000u);
    l = (short)f2b(v - hf);
}

// ============ prep: conv + w3 weights ============
__global__ __launch_bounds__(256) void prep_w(
    const float* __restrict__ w1, const float* __restrict__ w2, const float* __restrict__ w3,
    const float* __restrict__ ew3,
    unsigned short* __restrict__ wb1h, unsigned short* __restrict__ wb1l,
    unsigned short* __restrict__ w2h, unsigned short* __restrict__ w2l,
    unsigned short* __restrict__ w3h, unsigned short* __restrict__ w3l,
    float* __restrict__ w3t) {
    int tid = blockIdx.x * 256 + threadIdx.x;
    if (tid < 8192) {
        int k = tid >> 8, r = tid & 255;
        int c = r >> 6, ky = (r >> 3) & 7, kx = r & 7;
        float v = w1[tid];
        unsigned short h = f2b(v);
        int d = ((ky * 2 + (k >> 4)) * 16 + (k & 15)) * 32 + c * 8 + kx;
        wb1h[d] = h;
        wb1l[d] = f2b(v - b2f(h));
    } else if (tid < 8192 + 32768) {
        int i = tid - 8192;
        int n = i >> 9, r = i & 511;
        int c = r >> 4, ky = (r >> 2) & 3, kx = r & 3;
        float v = w2[i];
        unsigned short h = f2b(v);
        int d = ((ky * 4 + kx) * 64 + n) * 32 + c;
        w2h[d] = h;
        w2l[d] = f2b(v - b2f(h));
    } else if (tid < 8192 + 32768 + 36864) {
        int i = tid - 40960;
        int n = i / 576, r = i - n * 576;
        int c = r / 9, s = r - c * 9;
        int ky = s / 3, kx = s - ky * 3;
        float v = w3[i];
        unsigned short h = f2b(v);
        int d = (((ky * 3 + kx) * 2 + (c >> 5)) * 64 + n) * 32 + (c & 31);
        w3h[d] = h;
        w3l[d] = f2b(v - b2f(h));
    } else if (tid < 77824 + 36864) {
        int i = tid - 77824;
        int e = i / 6144, rem = i - e * 6144;
        int a = rem >> 9, k = rem & 511;
        w3t[i] = ew3[e * 6144 + k * 12 + a];
    }
}

// ============ prep: fc weights: fc_w[(c*49+p)*512+n] -> fcw[n][(p*64+c)] hi/lo ============
__global__ __launch_bounds__(256) void prep_fcw(
    const float* __restrict__ fw, unsigned short* __restrict__ h, unsigned short* __restrict__ l) {
    __shared__ float tile[64][65];
    int k0 = blockIdx.x * 64;
    int n0 = blockIdx.y * 64;
    int tx = threadIdx.x & 63, ty = threadIdx.x >> 6;
#pragma unroll
    for (int j = 0; j < 16; j++) {
        int kk = ty + j * 4;
        int kp = k0 + kk;
        int p = kp >> 6, c = kp & 63;
        tile[kk][tx] = fw[(c * 49 + p) * 512 + n0 + tx];
    }
    __syncthreads();
#pragma unroll
    for (int j = 0; j < 16; j++) {
        int r = ty + j * 4;
        float v = tile[tx][r];
        unsigned short hh = f2b(v);
        long d = (long)(n0 + r) * 3136 + k0 + tx;
        h[d] = hh;
        l[d] = f2b(v - b2f(hh));
    }
}

// ============ prep: expert weights [e][d][h] -> bf16 [e][h][d] ============
__global__ __launch_bounds__(256) void prep_ewT(
    const float* __restrict__ ew1, const float* __restrict__ ew2,
    unsigned short* __restrict__ t1, unsigned short* __restrict__ t2) {
    __shared__ float tile[32][33];
    int z = blockIdx.z;
    int e = z % 6;
    const float* src = (z < 6) ? (ew1 + e * 262144) : (ew2 + e * 262144);
    unsigned short* dst = (z < 6) ? (t1 + e * 262144) : (t2 + e * 262144);
    int d0 = blockIdx.y * 32;
    int h0 = blockIdx.x * 32;
    int tx = threadIdx.x, ty = threadIdx.y;
#pragma unroll
    for (int j = 0; j < 4; j++)
        tile[ty + j * 8][tx] = src[(d0 + ty + j * 8) * 512 + h0 + tx];
    __syncthreads();
#pragma unroll
    for (int j = 0; j < 4; j++)
        dst[(h0 + ty + j * 8) * 512 + (d0 + tx)] = f2b(tile[tx][ty + j * 8]);
}

// ============ conv1: direct MFMA. Weights in LDS (lgkmcnt path); x rows
// prefetched 2 deep on vmcnt so each wave keeps 16KB in flight. ============
__global__ __launch_bounds__(256, 3) void conv1_k(
    const float* __restrict__ x, const unsigned short* __restrict__ wbh,
    const unsigned short* __restrict__ wbl, const float* __restrict__ b1,
    unsigned short* __restrict__ yhi, unsigned short* __restrict__ ylo) {
    // [ky][table][lane] fragment-major: ds_read_b128 at lane*16 -> conflict-free
    __shared__ bf16x8 wlds[8][4][64];
    int t = threadIdx.x;
    {
        int tab = t >> 6, ln = t & 63;
        const unsigned short* sb = ((tab < 2) ? wbh : wbl) +
            ((ln & 15) * 32 + (ln >> 4) * 8 + (tab & 1) * 512);
#pragma unroll
        for (int k = 0; k < 8; k++)
            wlds[k][tab][ln] = *(const bf16x8*)(sb + k * 1024);
    }
    int wave = t >> 6, lane = t & 63, l16 = lane & 15, quad = lane >> 4;
    int px0 = blockIdx.x * 256 + wave * 64;
    const float* abase[4];
#pragma unroll
    for (int i = 0; i < 4; i++) {
        int px = px0 + i * 16 + l16;
        int n = px / 400;
        int rem = px - n * 400;
        int oy = rem / 20;
        int ox = rem - oy * 20;
        abase[i] = x + (long)n * 28224 + quad * 7056 + oy * 4 * 84 + ox * 4;
    }
    f32x4 acc[4][2];
#pragma unroll
    for (int i = 0; i < 4; i++)
#pragma unroll
        for (int j = 0; j < 2; j++)
#pragma unroll
            for (int r = 0; r < 4; r++) acc[i][j][r] = 0.f;
    __syncthreads();
    float4 cur[8], nx1[8];
#pragma unroll
    for (int i = 0; i < 4; i++) {
        cur[i * 2] = *(const float4*)abase[i];
        cur[i * 2 + 1] = *(const float4*)(abase[i] + 4);
        nx1[i * 2] = *(const float4*)(abase[i] + 84);
        nx1[i * 2 + 1] = *(const float4*)(abase[i] + 88);
    }
#pragma unroll
    for (int ky = 0; ky < 8; ky++) {
        float4 nx2[8];
        if (ky < 6) {
#pragma unroll
            for (int i = 0; i < 4; i++) {
                const float* p = abase[i] + (ky + 2) * 84;
                nx2[i * 2] = *(const float4*)p;
                nx2[i * 2 + 1] = *(const float4*)(p + 4);
            }
        }
        bf16x8 bh0 = wlds[ky][0][lane];
        bf16x8 bh1 = wlds[ky][1][lane];
        bf16x8 bl0 = wlds[ky][2][lane];
        bf16x8 bl1 = wlds[ky][3][lane];
        bf16x8 ah[4], al[4];
#pragma unroll
        for (int i = 0; i < 4; i++) {
            float v[8] = {cur[i * 2].x, cur[i * 2].y, cur[i * 2].z, cur[i * 2].w,
                          cur[i * 2 + 1].x, cur[i * 2 + 1].y, cur[i * 2 + 1].z, cur[i * 2 + 1].w};
#pragma unroll
            for (int j = 0; j < 8; j++) {
                short hh, ll;
                split_trunc(v[j], hh, ll);
                ah[i][j] = hh;
                al[i][j] = ll;
            }
        }
#pragma unroll
        for (int i = 0; i < 4; i++) {
            acc[i][0] = __builtin_amdgcn_mfma_f32_16x16x32_bf16(ah[i], bh0, acc[i][0], 0, 0, 0);
            acc[i][0] = __builtin_amdgcn_mfma_f32_16x16x32_bf16(al[i], bh0, acc[i][0], 0, 0, 0);
            acc[i][0] = __builtin_amdgcn_mfma_f32_16x16x32_bf16(ah[i], bl0, acc[i][0], 0, 0, 0);
            acc[i][1] = __builtin_amdgcn_mfma_f32_16x16x32_bf16(ah[i], bh1, acc[i][1], 0, 0, 0);
            acc[i][1] = __builtin_amdgcn_mfma_f32_16x16x32_bf16(al[i], bh1, acc[i][1], 0, 0, 0);
            acc[i][1] = __builtin_amdgcn_mfma_f32_16x16x32_bf16(ah[i], bl1, acc[i][1], 0, 0, 0);
        }
        if (ky < 7) {
#pragma unroll
            for (int q = 0; q < 8; q++) cur[q] = nx1[q];
            if (ky < 6) {
#pragma unroll
                for (int q = 0; q < 8; q++) nx1[q] = nx2[q];
            }
        }
    }
    float bias0 = b1[l16], bias1 = b1[16 + l16];
#pragma unroll
    for (int i = 0; i < 4; i++) {
#pragma unroll
        for (int r = 0; r < 4; r++) {
            long px = px0 + i * 16 + quad * 4 + r;
            long o = px * 32;
            float v0 = fmaxf(acc[i][0][r] + bias0, 0.f);
            float v1 = fmaxf(acc[i][1][r] + bias1, 0.f);
            short h0, l0, h1, l1;
            split_trunc(v0, h0, l0);
            split_trunc(v1, h1, l1);
            yhi[o + l16] = (unsigned short)h0;
            ylo[o + l16] = (unsigned short)l0;
            yhi[o + 16 + l16] = (unsigned short)h1;
            ylo[o + 16 + l16] = (unsigned short)l1;
        }
    }
}

// ============ conv2/3: 4-wave blocks, B double-buffered in LDS (reg-staged,
// write-late), raw barrier with lgkmcnt-only drain: A prefetch for ck+1 stays
// in flight on vmcnt across the barrier. Each wave owns 64 px. ============
template <int C, int IH, int IW, int OH, int OW, int S, int KH, int KW>
__global__ __launch_bounds__(256, 2) void convm_k(
    const unsigned short* __restrict__ xhi, const unsigned short* __restrict__ xlo,
    const unsigned short* __restrict__ whi, const unsigned short* __restrict__ wlo,
    const float* __restrict__ bias,
    unsigned short* __restrict__ yhi, unsigned short* __restrict__ ylo) {
    constexpr int CH = C / 32;
    constexpr int NCHUNK = KH * KW * CH;
    // [buf][hi/lo][kquad][ch][8]: ds_read_b128 spreads 8 words/bank (minimum)
    __shared__ unsigned short Bst[2][2][4][64][8];
    int t = threadIdx.x;
    int wave = t >> 6, lane = t & 63, l16 = lane & 15, quad = lane >> 4;
    int pxbase = blockIdx.x * 256 + wave * 64;
    long xoff[4];
#pragma unroll
    for (int i = 0; i < 4; i++) {
        int px = pxbase + i * 16 + l16;
        int n = px / (OH * OW);
        int rem = px - n * (OH * OW);
        int oy = rem / OW;
        int ox = rem - oy * OW;
        xoff[i] = (((long)n * IH + oy * S) * IW + ox * S) * C + quad * 8;
    }
    f32x4 acc[4][4];
#pragma unroll
    for (int i = 0; i < 4; i++)
#pragma unroll
        for (int j = 0; j < 4; j++)
#pragma unroll
            for (int r = 0; r < 4; r++) acc[i][j][r] = 0.f;
    // prologue: stage B(0), load A(0)
    long wsrc = (long)lane * 32 + wave * 8;
    uint4 sh = *(const uint4*)(whi + wsrc);
    uint4 sl = *(const uint4*)(wlo + wsrc);
    bf16x8 a_h[4], a_l[4];
    {
        // koffset(0) == 0
#pragma unroll
        for (int i = 0; i < 4; i++) {
            a_h[i] = *(const bf16x8*)(xhi + xoff[i]);
            a_l[i] = *(const bf16x8*)(xlo + xoff[i]);
        }
    }
    *(uint4*)&Bst[0][0][wave][lane][0] = sh;
    *(uint4*)&Bst[0][1][wave][lane][0] = sl;
    asm volatile("s_waitcnt lgkmcnt(0)\n\ts_barrier" ::: "memory");
#pragma unroll
    for (int ck = 0; ck < NCHUNK; ck++) {
        const int cur = ck & 1;
        uint4 nsh, nsl;
        bf16x8 na_h[4], na_l[4];
        if (ck + 1 < NCHUNK) {
            long ws = (long)(ck + 1) * 2048 + lane * 32 + wave * 8;
            nsh = *(const uint4*)(whi + ws);
            nsl = *(const uint4*)(wlo + ws);
            int ck1 = ck + 1;
            int kyx = ck1 / CH;
            int ch = ck1 - kyx * CH;
            int ky = kyx / KW, kx = kyx - ky * KW;
            long k1 = ((long)(ky * IW + kx)) * C + ch * 32;
#pragma unroll
            for (int i = 0; i < 4; i++) {
                na_h[i] = *(const bf16x8*)(xhi + xoff[i] + k1);
                na_l[i] = *(const bf16x8*)(xlo + xoff[i] + k1);
            }
        }
        bf16x8 bh[4], bl[4];
#pragma unroll
        for (int j = 0; j < 4; j++) {
            bh[j] = *(const bf16x8*)&Bst[cur][0][quad][j * 16 + l16][0];
            bl[j] = *(const bf16x8*)&Bst[cur][1][quad][j * 16 + l16][0];
        }
#pragma unroll
        for (int i = 0; i < 4; i++)
#pragma unroll
            for (int j = 0; j < 4; j++) {
                acc[i][j] = __builtin_amdgcn_mfma_f32_16x16x32_bf16(a_h[i], bh[j], acc[i][j], 0, 0, 0);
                acc[i][j] = __builtin_amdgcn_mfma_f32_16x16x32_bf16(a_h[i], bl[j], acc[i][j], 0, 0, 0);
                acc[i][j] = __builtin_amdgcn_mfma_f32_16x16x32_bf16(a_l[i], bh[j], acc[i][j], 0, 0, 0);
            }
        if (ck + 1 < NCHUNK) {
            __builtin_amdgcn_sched_barrier(0);
            *(uint4*)&Bst[cur ^ 1][0][wave][lane][0] = nsh;
            *(uint4*)&Bst[cur ^ 1][1][wave][lane][0] = nsl;
            asm volatile("s_waitcnt lgkmcnt(0)\n\ts_barrier" ::: "memory");
#pragma unroll
            for (int i = 0; i < 4; i++) {
                a_h[i] = na_h[i];
                a_l[i] = na_l[i];
            }
        }
    }
#pragma unroll
    for (int i = 0; i < 4; i++)
#pragma unroll
        for (int j = 0; j < 4; j++) {
            int col = j * 16 + l16;
            float bv = bias[col];
#pragma unroll
            for (int r = 0; r < 4; r++) {
                int prow = pxbase + i * 16 + quad * 4 + r;
                float v = fmaxf(acc[i][j][r] + bv, 0.f);
                unsigned short h = f2b(v);
                yhi[(long)prow * 64 + col] = h;
                ylo[(long)prow * 64 + col] = f2b(v - b2f(h));
            }
        }
}

// ============ fc: LDS-free split-bf16 MFMA, 1 wave per block, K-split x7 ============
__global__ __launch_bounds__(64, 3) void fc_k(
    const unsigned short* __restrict__ Ahi, const unsigned short* __restrict__ Alo,
    const unsigned short* __restrict__ Bhi, const unsigned short* __restrict__ Blo,
    float* __restrict__ Cp) {
    int lane = threadIdx.x, l16 = lane & 15, quad = lane >> 4;
    int m0 = blockIdx.x * 64, n0 = blockIdx.y * 64;
    int z = blockIdx.z;
    int kBase = z * 448;
    f32x4 acc[4][4];
#pragma unroll
    for (int i = 0; i < 4; i++)
#pragma unroll
        for (int j = 0; j < 4; j++)
#pragma unroll
            for (int r = 0; r < 4; r++) acc[i][j][r] = 0.f;
#pragma unroll 2
    for (int k0 = kBase; k0 < kBase + 448; k0 += 32) {
        bf16x8 ah[4], al[4], bh[4], bl[4];
#pragma unroll
        for (int i = 0; i < 4; i++) {
            long a = (long)(m0 + i * 16 + l16) * 3136 + k0 + quad * 8;
            ah[i] = *(const bf16x8*)(Ahi + a);
            al[i] = *(const bf16x8*)(Alo + a);
        }
#pragma unroll
        for (int j = 0; j < 4; j++) {
            long b = (long)(n0 + j * 16 + l16) * 3136 + k0 + quad * 8;
            bh[j] = *(const bf16x8*)(Bhi + b);
            bl[j] = *(const bf16x8*)(Blo + b);
        }
#pragma unroll
        for (int i = 0; i < 4; i++)
#pragma unroll
            for (int j = 0; j < 4; j++) {
                acc[i][j] = __builtin_amdgcn_mfma_f32_16x16x32_bf16(ah[i], bh[j], acc[i][j], 0, 0, 0);
                acc[i][j] = __builtin_amdgcn_mfma_f32_16x16x32_bf16(ah[i], bl[j], acc[i][j], 0, 0, 0);
                acc[i][j] = __builtin_amdgcn_mfma_f32_16x16x32_bf16(al[i], bh[j], acc[i][j], 0, 0, 0);
            }
    }
    float* Cz = Cp + (long)z * 1048576;
#pragma unroll
    for (int i = 0; i < 4; i++)
#pragma unroll
        for (int j = 0; j < 4; j++) {
            int col = n0 + j * 16 + l16;
#pragma unroll
            for (int r = 0; r < 4; r++) {
                int row = m0 + i * 16 + quad * 4 + r;
                Cz[row * 512 + col] = acc[i][j][r];
            }
        }
}

// ============ fc finalize: sum 7 partials + bias + relu; also zero moe counters ============
__global__ __launch_bounds__(256) void fc_fin(
    const float* __restrict__ Cp, const float* __restrict__ bias,
    float* __restrict__ f, unsigned short* __restrict__ fb, int* __restrict__ cnt) {
    if (blockIdx.x == 0 && threadIdx.x < 8) cnt[threadIdx.x] = 0;
    int tid = blockIdx.x * 256 + threadIdx.x;
    int col = tid & 511;
    float v = bias[col];
#pragma unroll
    for (int z = 0; z < 7; z++) v += Cp[tid + (long)z * 1048576];
    v = fmaxf(v, 0.f);
    f[tid] = v;
    fb[tid] = f2b(v);
}

// ============ gate: top-2 + expert-row compaction ============
__global__ __launch_bounds__(256) void gate_k(
    const float* __restrict__ f, const float* __restrict__ gw, const float* __restrict__ gb,
    int* __restrict__ topi, float* __restrict__ topp,
    int* __restrict__ cnt, int* __restrict__ rowlist, int* __restrict__ slotp) {
    int wave = threadIdx.x >> 6, lane = threadIdx.x & 63;
    int row = blockIdx.x * 4 + wave;
    float fv[8];
#pragma unroll
    for (int j = 0; j < 8; j++) fv[j] = f[row * 512 + lane + 64 * j];
    float lg[6];
#pragma unroll
    for (int e = 0; e < 6; e++) {
        float a = 0.f;
#pragma unroll
        for (int j = 0; j < 8; j++) a += fv[j] * gw[(lane + 64 * j) * 6 + e];
#pragma unroll
        for (int off = 32; off > 0; off >>= 1) a += __shfl_xor(a, off, 64);
        lg[e] = a + gb[e];
    }
    if (lane == 0) {
        int i1 = 0;
        float v1 = lg[0];
#pragma unroll
        for (int e = 1; e < 6; e++)
            if (lg[e] > v1) { v1 = lg[e]; i1 = e; }
        int i2 = (i1 == 0) ? 1 : 0;
        float v2 = lg[i2];
#pragma unroll
        for (int e = 0; e < 6; e++)
            if (e != i1 && lg[e] > v2) { v2 = lg[e]; i2 = e; }
        float pa = 1.f / (1.f + expf(v2 - v1));
        topi[row * 2] = i1;
        topi[row * 2 + 1] = i2;
        topp[row * 2] = pa;
        topp[row * 2 + 1] = 1.f - pa;
        int s1 = atomicAdd(cnt + i1, 1);
        int s2 = atomicAdd(cnt + i2, 1);
        rowlist[i1 * 2048 + s1] = row;
        rowlist[i2 * 2048 + s2] = row;
        slotp[row * 2] = s1;
        slotp[row * 2 + 1] = s2;
    }
}

// ============ expert GEMM: compacted rows; gather A when rowlist != null ============
__global__ __launch_bounds__(64, 4) void moe_gemm(
    const unsigned short* __restrict__ A, long aStride,
    const unsigned short* __restrict__ Bt, const float* __restrict__ bias,
    unsigned short* __restrict__ C,
    const int* __restrict__ cnt, const int* __restrict__ rowlist) {
    int e = blockIdx.z;
    int ne = cnt[e];
    int m0 = blockIdx.x * 64;
    if (m0 >= ne) return;
    const unsigned short* Ae = A + (long)e * aStride;
    const unsigned short* Be = Bt + (long)e * 262144;
    const float* be = bias + e * 512;
    unsigned short* Ce = C + (long)e * 2048 * 512;
    int lane = threadIdx.x, l16 = lane & 15, quad = lane >> 4;
    int n0 = blockIdx.y * 64;
    int arow[4];
#pragma unroll
    for (int i = 0; i < 4; i++) {
        int slot = m0 + i * 16 + l16;
        arow[i] = rowlist ? ((slot < ne) ? rowlist[e * 2048 + slot] : 0) : slot;
    }
    f32x4 acc[4][4];
#pragma unroll
    for (int i = 0; i < 4; i++)
#pragma unroll
        for (int j = 0; j < 4; j++)
#pragma unroll
            for (int r = 0; r < 4; r++) acc[i][j][r] = 0.f;
#pragma unroll 4
    for (int k0 = 0; k0 < 512; k0 += 32) {
        bf16x8 a[4], b[4];
#pragma unroll
        for (int i = 0; i < 4; i++)
            a[i] = *(const bf16x8*)(Ae + (long)arow[i] * 512 + k0 + quad * 8);
#pragma unroll
        for (int j = 0; j < 4; j++)
            b[j] = *(const bf16x8*)(Be + (long)(n0 + j * 16 + l16) * 512 + k0 + quad * 8);
#pragma unroll
        for (int i = 0; i < 4; i++)
#pragma unroll
            for (int j = 0; j < 4; j++)
                acc[i][j] = __builtin_amdgcn_mfma_f32_16x16x32_bf16(a[i], b[j], acc[i][j], 0, 0, 0);
    }
#pragma unroll
    for (int i = 0; i < 4; i++)
#pragma unroll
        for (int j = 0; j < 4; j++) {
            int col = n0 + j * 16 + l16;
            float bcol = be[col];
#pragma unroll
            for (int r = 0; r < 4; r++) {
                int row = m0 + i * 16 + quad * 4 + r;
                float v = fmaxf(acc[i][j][r] + bcol, 0.f);
                Ce[(long)row * 512 + col] = f2b(v);
            }
        }
}

// ============ combine: wave per row, coalesced, shuffle-reduce ============
__global__ __launch_bounds__(256) void combine_k(
    const unsigned short* __restrict__ h2, const float* __restrict__ w3t,
    const float* __restrict__ b3, const int* __restrict__ topi,
    const float* __restrict__ topp, const int* __restrict__ slotp,
    float* __restrict__ out) {
    int b = blockIdx.x * 4 + (threadIdx.x >> 6);
    int lane = threadIdx.x & 63;
    int e0 = topi[b * 2], e1 = topi[b * 2 + 1];
    float p0 = topp[b * 2], p1 = topp[b * 2 + 1];
    int s0 = slotp[b * 2], s1 = slotp[b * 2 + 1];
    float r[12];
#pragma unroll
    for (int a = 0; a < 12; a++) r[a] = 0.f;
#pragma unroll
    for (int j = 0; j < 2; j++) {
        int e = j ? e1 : e0;
        int s = j ? s1 : s0;
        float p = j ? p1 : p0;
        const unsigned short* hp = h2 + ((long)e * 2048 + s) * 512 + lane * 8;
        bf16x8 hv = *(const bf16x8*)hp;
        float hf[8];
#pragma unroll
        for (int q = 0; q < 8; q++) hf[q] = b2f((unsigned short)hv[q]);
        const float* wb = w3t + e * 6144 + lane * 8;
#pragma unroll
        for (int a = 0; a < 12; a++) {
            float4 w0 = *(const float4*)(wb + a * 512);
            float4 w1 = *(const float4*)(wb + a * 512 + 4);
            float acc = hf[0] * w0.x + hf[1] * w0.y + hf[2] * w0.z + hf[3] * w0.w +
                        hf[4] * w1.x + hf[5] * w1.y + hf[6] * w1.z + hf[7] * w1.w;
            r[a] += p * acc;
        }
    }
#pragma unroll
    for (int a = 0; a < 12; a++)
#pragma unroll
        for (int off = 32; off > 0; off >>= 1) r[a] += __shfl_xor(r[a], off, 64);
    float v = 0.f;
#pragma unroll
    for (int a = 0; a < 12; a++)
        if (lane == a) v = r[a];
    if (lane < 12)
        out[b * 12 + lane] = v + p0 * b3[e0 * 12 + lane] + p1 * b3[e1 * 12 + lane];
}

extern "C" void kernel_launch(void* const* d_in, const int* in_sizes, int n_in,
                              void* d_out, int out_size, void* d_ws, size_t ws_size,
                              hipStream_t stream) {
    const float* x   = (const float*)d_in[0];
    const float* c1w = (const float*)d_in[1];
    const float* c1b = (const float*)d_in[2];
    const float* c2w = (const float*)d_in[3];
    const float* c2b = (const float*)d_in[4];
    const float* c3w = (const float*)d_in[5];
    const float* c3b = (const float*)d_in[6];
    const float* fcw = (const float*)d_in[7];
    const float* fcb = (const float*)d_in[8];
    const float* gw  = (const float*)d_in[9];
    const float* gb  = (const float*)d_in[10];
    const float* ew1 = (const float*)d_in[11];
    const float* eb1 = (const float*)d_in[12];
    const float* ew2 = (const float*)d_in[13];
    const float* eb2 = (const float*)d_in[14];
    const float* ew3 = (const float*)d_in[15];
    const float* eb3 = (const float*)d_in[16];

    char* ws = (char*)d_ws;
    unsigned short* y1hi = (unsigned short*)(ws + 0L);          // 52428800 B
    unsigned short* y1lo = (unsigned short*)(ws + 52428800L);   // 52428800 B
    unsigned short* f3hi = (unsigned short*)(ws + 0L);          // alias (y1 dead after conv2)
    unsigned short* f3lo = (unsigned short*)(ws + 12845056L);   // alias
    // moe routing aux: dead region after conv2 (y1hi tail), written from fc_fin on.
    int*   cnt           = (int*)(ws + 26214400L);              // 32 B
    int*   rowlist       = (int*)(ws + 26214464L);              // 49152 B
    int*   slotp         = (int*)(ws + 26263616L);              // 16384 B
    unsigned short* y2hi = (unsigned short*)(ws + 104857600L);  // 21233664 B
    unsigned short* y2lo = (unsigned short*)(ws + 126091264L);  // 21233664 B
    unsigned short* h1   = (unsigned short*)(ws + 104857600L);  // alias (y2 dead after conv3)
    unsigned short* h2   = (unsigned short*)(ws + 117440512L);  // alias
    float* f             = (float*)(ws + 147324928L);           // 4194304 B
    unsigned short* fb   = (unsigned short*)(ws + 151519232L);  // 2097152 B
    int*   topi          = (int*)(ws + 153616384L);             // 16384 B
    float* topp          = (float*)(ws + 153632768L);           // 16384 B
    unsigned short* w2h  = (unsigned short*)(ws + 153681920L);  // 65536 B
    unsigned short* w2l  = (unsigned short*)(ws + 153747456L);  // 65536 B
    unsigned short* w3h  = (unsigned short*)(ws + 153812992L);  // 73728 B
    unsigned short* w3l  = (unsigned short*)(ws + 153886720L);  // 73728 B
    unsigned short* fcwh = (unsigned short*)(ws + 153960448L);  // 3211264 B
    unsigned short* fcwl = (unsigned short*)(ws + 157171712L);  // 3211264 B
    unsigned short* ew1t = (unsigned short*)(ws + 160382976L);  // 3145728 B
    unsigned short* ew2t = (unsigned short*)(ws + 163528704L);  // 3145728 B
    float* w3t           = (float*)(ws + 166674432L);           // 147456 B
    float* Cp            = (float*)(ws + 166821888L);           // 7*4194304 = 29360128 B
    unsigned short* wb1h = (unsigned short*)(ws + 196182016L);  // 16384 B
    unsigned short* wb1l = (unsigned short*)(ws + 196198400L);  // 16384 B (end 196214784)
    float* out = (float*)d_out;

    hipLaunchKernelGGL(prep_w, dim3(448), dim3(256), 0, stream, c1w, c2w, c3w, ew3,
                       wb1h, wb1l, w2h, w2l, w3h, w3l, w3t);
    hipLaunchKernelGGL(prep_fcw, dim3(49, 8), dim3(256), 0, stream, fcw, fcwh, fcwl);
    hipLaunchKernelGGL(prep_ewT, dim3(16, 16, 12), dim3(32, 8), 0, stream, ew1, ew2, ew1t, ew2t);
    hipLaunchKernelGGL(conv1_k, dim3(3200), dim3(256), 0, stream, x, wb1h, wb1l, c1b, y1hi, y1lo);
    hipLaunchKernelGGL((convm_k<32, 20, 20, 9, 9, 2, 4, 4>), dim3(648), dim3(256), 0, stream,
                       y1hi, y1lo, w2h, w2l, c2b, y2hi, y2lo);
    hipLaunchKernelGGL((convm_k<64, 9, 9, 7, 7, 1, 3, 3>), dim3(392), dim3(256), 0, stream,
                       y2hi, y2lo, w3h, w3l, c3b, f3hi, f3lo);
    hipLaunchKernelGGL(fc_k, dim3(32, 8, 7), dim3(64), 0, stream, f3hi, f3lo, fcwh, fcwl, Cp);
    hipLaunchKernelGGL(fc_fin, dim3(4096), dim3(256), 0, stream, Cp, fcb, f, fb, cnt);
    hipLaunchKernelGGL(gate_k, dim3(512), dim3(256), 0, stream, f, gw, gb, topi, topp,
                       cnt, rowlist, slotp);
    hipLaunchKernelGGL(moe_gemm, dim3(32, 8, 6), dim3(64), 0, stream, fb, 0L, ew1t, eb1, h1,
                       cnt, rowlist);
    hipLaunchKernelGGL(moe_gemm, dim3(32, 8, 6), dim3(64), 0, stream, h1, 1048576L, ew2t, eb2, h2,
                       cnt, (const int*)nullptr);
    hipLaunchKernelGGL(combine_k, dim3(512), dim3(256), 0, stream, h2, w3t, eb3, topi, topp,
                       slotp, out);
}

// Round 3
// 693.841 us; speedup vs baseline: 1.0591x; 1.0264x over previous
//
#include <hip/hip_runtime.h>
#include <hip/hip_bf16.h>
#include <math.h>

typedef __attribute__((ext_vector_type(8))) short bf16x8;
typedef __attribute__((ext_vector_type(4))) float f32x4;

__device__ __forceinline__ float b2f(unsigned short u) {
    unsigned int v = ((unsigned int)u) << 16;
    return __uint_as_float(v);
}
__device__ __forceinline__ unsigned short f2b(float f) {
    __hip_bfloat16 h = __float2bfloat16(f);
    return *reinterpret_cast<unsigned short*>(&h);
}
// truncation split: hi = top 16 bits, lo = RNE(v - hi). residual ~2^-17 |v|
__device__ __forceinline__ void split_trunc(float v, short& h, short& l) {
    unsigned int ui = __float_as_uint(v);
    h = (short)(ui >> 16);
    float hf = __uint_as_float(ui & 0xffff0000u);
    l = (short)f2b(v - hf);
}

// ============ prep: conv + w3 weights ============
__global__ __launch_bounds__(256) void prep_w(
    const float* __restrict__ w1, const float* __restrict__ w2, const float* __restrict__ w3,
    const float* __restrict__ ew3,
    unsigned short* __restrict__ wb1h, unsigned short* __restrict__ wb1l,
    unsigned short* __restrict__ w2h, unsigned short* __restrict__ w2l,
    unsigned short* __restrict__ w3h, unsigned short* __restrict__ w3l,
    float* __restrict__ w3t) {
    int tid = blockIdx.x * 256 + threadIdx.x;
    if (tid < 8192) {
        int k = tid >> 8, r = tid & 255;
        int c = r >> 6, ky = (r >> 3) & 7, kx = r & 7;
        float v = w1[tid];
        unsigned short h = f2b(v);
        int d = ((ky * 2 + (k >> 4)) * 16 + (k & 15)) * 32 + c * 8 + kx;
        wb1h[d] = h;
        wb1l[d] = f2b(v - b2f(h));
    } else if (tid < 8192 + 32768) {
        int i = tid - 8192;
        int n = i >> 9, r = i & 511;
        int c = r >> 4, ky = (r >> 2) & 3, kx = r & 3;
        float v = w2[i];
        unsigned short h = f2b(v);
        int d = ((ky * 4 + kx) * 64 + n) * 32 + c;
        w2h[d] = h;
        w2l[d] = f2b(v - b2f(h));
    } else if (tid < 8192 + 32768 + 36864) {
        int i = tid - 40960;
        int n = i / 576, r = i - n * 576;
        int c = r / 9, s = r - c * 9;
        int ky = s / 3, kx = s - ky * 3;
        float v = w3[i];
        unsigned short h = f2b(v);
        int d = (((ky * 3 + kx) * 2 + (c >> 5)) * 64 + n) * 32 + (c & 31);
        w3h[d] = h;
        w3l[d] = f2b(v - b2f(h));
    } else if (tid < 77824 + 36864) {
        int i = tid - 77824;
        int e = i / 6144, rem = i - e * 6144;
        int a = rem >> 9, k = rem & 511;
        w3t[i] = ew3[e * 6144 + k * 12 + a];
    }
}

// ============ prep: fc weights: fc_w[(c*49+p)*512+n] -> fcw[n][(p*64+c)] hi/lo ============
__global__ __launch_bounds__(256) void prep_fcw(
    const float* __restrict__ fw, unsigned short* __restrict__ h, unsigned short* __restrict__ l) {
    __shared__ float tile[64][65];
    int k0 = blockIdx.x * 64;
    int n0 = blockIdx.y * 64;
    int tx = threadIdx.x & 63, ty = threadIdx.x >> 6;
#pragma unroll
    for (int j = 0; j < 16; j++) {
        int kk = ty + j * 4;
        int kp = k0 + kk;
        int p = kp >> 6, c = kp & 63;
        tile[kk][tx] = fw[(c * 49 + p) * 512 + n0 + tx];
    }
    __syncthreads();
#pragma unroll
    for (int j = 0; j < 16; j++) {
        int r = ty + j * 4;
        float v = tile[tx][r];
        unsigned short hh = f2b(v);
        long d = (long)(n0 + r) * 3136 + k0 + tx;
        h[d] = hh;
        l[d] = f2b(v - b2f(hh));
    }
}

// ============ prep: expert weights [e][d][h] -> bf16 [e][h][d] ============
__global__ __launch_bounds__(256) void prep_ewT(
    const float* __restrict__ ew1, const float* __restrict__ ew2,
    unsigned short* __restrict__ t1, unsigned short* __restrict__ t2) {
    __shared__ float tile[32][33];
    int z = blockIdx.z;
    int e = z % 6;
    const float* src = (z < 6) ? (ew1 + e * 262144) : (ew2 + e * 262144);
    unsigned short* dst = (z < 6) ? (t1 + e * 262144) : (t2 + e * 262144);
    int d0 = blockIdx.y * 32;
    int h0 = blockIdx.x * 32;
    int tx = threadIdx.x, ty = threadIdx.y;
#pragma unroll
    for (int j = 0; j < 4; j++)
        tile[ty + j * 8][tx] = src[(d0 + ty + j * 8) * 512 + h0 + tx];
    __syncthreads();
#pragma unroll
    for (int j = 0; j < 4; j++)
        dst[(h0 + ty + j * 8) * 512 + (d0 + tx)] = f2b(tile[tx][ty + j * 8]);
}

// ============ conv1: direct MFMA. Weights in LDS (lgkmcnt path). x rows in a
// 3-deep register ring; load issue PINNED 2 iterations ahead of use with
// sched_barrier(0) brackets so the scheduler cannot sink the prefetch (the
// r2 version's depth-2 was sunk: VGPR=52 proved the ring never existed).
// 32 px/wave keeps the ring + acc under ~128 VGPR for 4 waves/SIMD. ============
__global__ __launch_bounds__(256, 4) void conv1_k(
    const float* __restrict__ x, const unsigned short* __restrict__ wbh,
    const unsigned short* __restrict__ wbl, const float* __restrict__ b1,
    unsigned short* __restrict__ yhi, unsigned short* __restrict__ ylo) {
    // [ky][table][lane] fragment-major: ds_read_b128 at lane*16 -> conflict-free
    __shared__ bf16x8 wlds[8][4][64];
    int t = threadIdx.x;
    {
        int tab = t >> 6, ln = t & 63;
        const unsigned short* sb = ((tab < 2) ? wbh : wbl) +
            ((ln & 15) * 32 + (ln >> 4) * 8 + (tab & 1) * 512);
#pragma unroll
        for (int k = 0; k < 8; k++)
            wlds[k][tab][ln] = *(const bf16x8*)(sb + k * 1024);
    }
    int wave = t >> 6, lane = t & 63, l16 = lane & 15, quad = lane >> 4;
    int px0 = blockIdx.x * 128 + wave * 32;
    const float* abase[2];
#pragma unroll
    for (int i = 0; i < 2; i++) {
        int px = px0 + i * 16 + l16;
        int n = px / 400;
        int rem = px - n * 400;
        int oy = rem / 20;
        int ox = rem - oy * 20;
        abase[i] = x + (long)n * 28224 + quad * 7056 + oy * 4 * 84 + ox * 4;
    }
    f32x4 acc[2][2];
#pragma unroll
    for (int i = 0; i < 2; i++)
#pragma unroll
        for (int j = 0; j < 2; j++)
#pragma unroll
            for (int r = 0; r < 4; r++) acc[i][j][r] = 0.f;
    __syncthreads();
    float4 buf[3][4];  // [row%3][frag*2+half] ring, indices compile-time after unroll
    // prologue: issue rows 0 and 1, pinned
#pragma unroll
    for (int r = 0; r < 2; r++) {
        __builtin_amdgcn_sched_barrier(0);
#pragma unroll
        for (int i = 0; i < 2; i++) {
            const float* p = abase[i] + r * 84;
            buf[r][i * 2] = *(const float4*)p;
            buf[r][i * 2 + 1] = *(const float4*)(p + 4);
        }
        __builtin_amdgcn_sched_barrier(0);
    }
#pragma unroll
    for (int ky = 0; ky < 8; ky++) {
        if (ky < 6) {
            __builtin_amdgcn_sched_barrier(0);
#pragma unroll
            for (int i = 0; i < 2; i++) {
                const float* p = abase[i] + (ky + 2) * 84;
                buf[(ky + 2) % 3][i * 2] = *(const float4*)p;
                buf[(ky + 2) % 3][i * 2 + 1] = *(const float4*)(p + 4);
            }
            __builtin_amdgcn_sched_barrier(0);
        }
        bf16x8 bh0 = wlds[ky][0][lane];
        bf16x8 bh1 = wlds[ky][1][lane];
        bf16x8 bl0 = wlds[ky][2][lane];
        bf16x8 bl1 = wlds[ky][3][lane];
        bf16x8 ah[2], al[2];
#pragma unroll
        for (int i = 0; i < 2; i++) {
            const float4& c0 = buf[ky % 3][i * 2];
            const float4& c1 = buf[ky % 3][i * 2 + 1];
            float v[8] = {c0.x, c0.y, c0.z, c0.w, c1.x, c1.y, c1.z, c1.w};
#pragma unroll
            for (int j = 0; j < 8; j++) {
                short hh, ll;
                split_trunc(v[j], hh, ll);
                ah[i][j] = hh;
                al[i][j] = ll;
            }
        }
#pragma unroll
        for (int i = 0; i < 2; i++) {
            acc[i][0] = __builtin_amdgcn_mfma_f32_16x16x32_bf16(ah[i], bh0, acc[i][0], 0, 0, 0);
            acc[i][0] = __builtin_amdgcn_mfma_f32_16x16x32_bf16(al[i], bh0, acc[i][0], 0, 0, 0);
            acc[i][0] = __builtin_amdgcn_mfma_f32_16x16x32_bf16(ah[i], bl0, acc[i][0], 0, 0, 0);
            acc[i][1] = __builtin_amdgcn_mfma_f32_16x16x32_bf16(ah[i], bh1, acc[i][1], 0, 0, 0);
            acc[i][1] = __builtin_amdgcn_mfma_f32_16x16x32_bf16(al[i], bh1, acc[i][1], 0, 0, 0);
            acc[i][1] = __builtin_amdgcn_mfma_f32_16x16x32_bf16(ah[i], bl1, acc[i][1], 0, 0, 0);
        }
    }
    float bias0 = b1[l16], bias1 = b1[16 + l16];
#pragma unroll
    for (int i = 0; i < 2; i++) {
#pragma unroll
        for (int r = 0; r < 4; r++) {
            long px = px0 + i * 16 + quad * 4 + r;
            long o = px * 32;
            float v0 = fmaxf(acc[i][0][r] + bias0, 0.f);
            float v1 = fmaxf(acc[i][1][r] + bias1, 0.f);
            short h0, l0, h1, l1;
            split_trunc(v0, h0, l0);
            split_trunc(v1, h1, l1);
            yhi[o + l16] = (unsigned short)h0;
            ylo[o + l16] = (unsigned short)l0;
            yhi[o + 16 + l16] = (unsigned short)h1;
            ylo[o + 16 + l16] = (unsigned short)l1;
        }
    }
}

// ============ conv2/3: 4-wave blocks, B double-buffered in LDS (reg-staged,
// write-late), raw barrier with lgkmcnt-only drain: A prefetch for ck+1 stays
// in flight on vmcnt across the barrier. Each wave owns 64 px. ============
template <int C, int IH, int IW, int OH, int OW, int S, int KH, int KW>
__global__ __launch_bounds__(256, 2) void convm_k(
    const unsigned short* __restrict__ xhi, const unsigned short* __restrict__ xlo,
    const unsigned short* __restrict__ whi, const unsigned short* __restrict__ wlo,
    const float* __restrict__ bias,
    unsigned short* __restrict__ yhi, unsigned short* __restrict__ ylo) {
    constexpr int CH = C / 32;
    constexpr int NCHUNK = KH * KW * CH;
    // [buf][hi/lo][kquad][ch][8]: ds_read_b128 spreads 8 words/bank (minimum)
    __shared__ unsigned short Bst[2][2][4][64][8];
    int t = threadIdx.x;
    int wave = t >> 6, lane = t & 63, l16 = lane & 15, quad = lane >> 4;
    int pxbase = blockIdx.x * 256 + wave * 64;
    long xoff[4];
#pragma unroll
    for (int i = 0; i < 4; i++) {
        int px = pxbase + i * 16 + l16;
        int n = px / (OH * OW);
        int rem = px - n * (OH * OW);
        int oy = rem / OW;
        int ox = rem - oy * OW;
        xoff[i] = (((long)n * IH + oy * S) * IW + ox * S) * C + quad * 8;
    }
    f32x4 acc[4][4];
#pragma unroll
    for (int i = 0; i < 4; i++)
#pragma unroll
        for (int j = 0; j < 4; j++)
#pragma unroll
            for (int r = 0; r < 4; r++) acc[i][j][r] = 0.f;
    // prologue: stage B(0), load A(0)
    long wsrc = (long)lane * 32 + wave * 8;
    uint4 sh = *(const uint4*)(whi + wsrc);
    uint4 sl = *(const uint4*)(wlo + wsrc);
    bf16x8 a_h[4], a_l[4];
    {
        // koffset(0) == 0
#pragma unroll
        for (int i = 0; i < 4; i++) {
            a_h[i] = *(const bf16x8*)(xhi + xoff[i]);
            a_l[i] = *(const bf16x8*)(xlo + xoff[i]);
        }
    }
    *(uint4*)&Bst[0][0][wave][lane][0] = sh;
    *(uint4*)&Bst[0][1][wave][lane][0] = sl;
    asm volatile("s_waitcnt lgkmcnt(0)\n\ts_barrier" ::: "memory");
#pragma unroll
    for (int ck = 0; ck < NCHUNK; ck++) {
        const int cur = ck & 1;
        uint4 nsh, nsl;
        bf16x8 na_h[4], na_l[4];
        if (ck + 1 < NCHUNK) {
            long ws = (long)(ck + 1) * 2048 + lane * 32 + wave * 8;
            nsh = *(const uint4*)(whi + ws);
            nsl = *(const uint4*)(wlo + ws);
            int ck1 = ck + 1;
            int kyx = ck1 / CH;
            int ch = ck1 - kyx * CH;
            int ky = kyx / KW, kx = kyx - ky * KW;
            long k1 = ((long)(ky * IW + kx)) * C + ch * 32;
#pragma unroll
            for (int i = 0; i < 4; i++) {
                na_h[i] = *(const bf16x8*)(xhi + xoff[i] + k1);
                na_l[i] = *(const bf16x8*)(xlo + xoff[i] + k1);
            }
        }
        bf16x8 bh[4], bl[4];
#pragma unroll
        for (int j = 0; j < 4; j++) {
            bh[j] = *(const bf16x8*)&Bst[cur][0][quad][j * 16 + l16][0];
            bl[j] = *(const bf16x8*)&Bst[cur][1][quad][j * 16 + l16][0];
        }
#pragma unroll
        for (int i = 0; i < 4; i++)
#pragma unroll
            for (int j = 0; j < 4; j++) {
                acc[i][j] = __builtin_amdgcn_mfma_f32_16x16x32_bf16(a_h[i], bh[j], acc[i][j], 0, 0, 0);
                acc[i][j] = __builtin_amdgcn_mfma_f32_16x16x32_bf16(a_h[i], bl[j], acc[i][j], 0, 0, 0);
                acc[i][j] = __builtin_amdgcn_mfma_f32_16x16x32_bf16(a_l[i], bh[j], acc[i][j], 0, 0, 0);
            }
        if (ck + 1 < NCHUNK) {
            __builtin_amdgcn_sched_barrier(0);
            *(uint4*)&Bst[cur ^ 1][0][wave][lane][0] = nsh;
            *(uint4*)&Bst[cur ^ 1][1][wave][lane][0] = nsl;
            asm volatile("s_waitcnt lgkmcnt(0)\n\ts_barrier" ::: "memory");
#pragma unroll
            for (int i = 0; i < 4; i++) {
                a_h[i] = na_h[i];
                a_l[i] = na_l[i];
            }
        }
    }
#pragma unroll
    for (int i = 0; i < 4; i++)
#pragma unroll
        for (int j = 0; j < 4; j++) {
            int col = j * 16 + l16;
            float bv = bias[col];
#pragma unroll
            for (int r = 0; r < 4; r++) {
                int prow = pxbase + i * 16 + quad * 4 + r;
                float v = fmaxf(acc[i][j][r] + bv, 0.f);
                unsigned short h = f2b(v);
                yhi[(long)prow * 64 + col] = h;
                ylo[(long)prow * 64 + col] = f2b(v - b2f(h));
            }
        }
}

// ============ fc: LDS-free split-bf16 MFMA, 1 wave per block, K-split x7 ============
__global__ __launch_bounds__(64, 3) void fc_k(
    const unsigned short* __restrict__ Ahi, const unsigned short* __restrict__ Alo,
    const unsigned short* __restrict__ Bhi, const unsigned short* __restrict__ Blo,
    float* __restrict__ Cp) {
    int lane = threadIdx.x, l16 = lane & 15, quad = lane >> 4;
    int m0 = blockIdx.x * 64, n0 = blockIdx.y * 64;
    int z = blockIdx.z;
    int kBase = z * 448;
    f32x4 acc[4][4];
#pragma unroll
    for (int i = 0; i < 4; i++)
#pragma unroll
        for (int j = 0; j < 4; j++)
#pragma unroll
            for (int r = 0; r < 4; r++) acc[i][j][r] = 0.f;
#pragma unroll 2
    for (int k0 = kBase; k0 < kBase + 448; k0 += 32) {
        bf16x8 ah[4], al[4], bh[4], bl[4];
#pragma unroll
        for (int i = 0; i < 4; i++) {
            long a = (long)(m0 + i * 16 + l16) * 3136 + k0 + quad * 8;
            ah[i] = *(const bf16x8*)(Ahi + a);
            al[i] = *(const bf16x8*)(Alo + a);
        }
#pragma unroll
        for (int j = 0; j < 4; j++) {
            long b = (long)(n0 + j * 16 + l16) * 3136 + k0 + quad * 8;
            bh[j] = *(const bf16x8*)(Bhi + b);
            bl[j] = *(const bf16x8*)(Blo + b);
        }
#pragma unroll
        for (int i = 0; i < 4; i++)
#pragma unroll
            for (int j = 0; j < 4; j++) {
                acc[i][j] = __builtin_amdgcn_mfma_f32_16x16x32_bf16(ah[i], bh[j], acc[i][j], 0, 0, 0);
                acc[i][j] = __builtin_amdgcn_mfma_f32_16x16x32_bf16(ah[i], bl[j], acc[i][j], 0, 0, 0);
                acc[i][j] = __builtin_amdgcn_mfma_f32_16x16x32_bf16(al[i], bh[j], acc[i][j], 0, 0, 0);
            }
    }
    float* Cz = Cp + (long)z * 1048576;
#pragma unroll
    for (int i = 0; i < 4; i++)
#pragma unroll
        for (int j = 0; j < 4; j++) {
            int col = n0 + j * 16 + l16;
#pragma unroll
            for (int r = 0; r < 4; r++) {
                int row = m0 + i * 16 + quad * 4 + r;
                Cz[row * 512 + col] = acc[i][j][r];
            }
        }
}

// ============ fc finalize: sum 7 partials + bias + relu; also zero moe counters ============
__global__ __launch_bounds__(256) void fc_fin(
    const float* __restrict__ Cp, const float* __restrict__ bias,
    float* __restrict__ f, unsigned short* __restrict__ fb, int* __restrict__ cnt) {
    if (blockIdx.x == 0 && threadIdx.x < 8) cnt[threadIdx.x] = 0;
    int tid = blockIdx.x * 256 + threadIdx.x;
    int col = tid & 511;
    float v = bias[col];
#pragma unroll
    for (int z = 0; z < 7; z++) v += Cp[tid + (long)z * 1048576];
    v = fmaxf(v, 0.f);
    f[tid] = v;
    fb[tid] = f2b(v);
}

// ============ gate: top-2 + expert-row compaction ============
__global__ __launch_bounds__(256) void gate_k(
    const float* __restrict__ f, const float* __restrict__ gw, const float* __restrict__ gb,
    int* __restrict__ topi, float* __restrict__ topp,
    int* __restrict__ cnt, int* __restrict__ rowlist, int* __restrict__ slotp) {
    int wave = threadIdx.x >> 6, lane = threadIdx.x & 63;
    int row = blockIdx.x * 4 + wave;
    float fv[8];
#pragma unroll
    for (int j = 0; j < 8; j++) fv[j] = f[row * 512 + lane + 64 * j];
    float lg[6];
#pragma unroll
    for (int e = 0; e < 6; e++) {
        float a = 0.f;
#pragma unroll
        for (int j = 0; j < 8; j++) a += fv[j] * gw[(lane + 64 * j) * 6 + e];
#pragma unroll
        for (int off = 32; off > 0; off >>= 1) a += __shfl_xor(a, off, 64);
        lg[e] = a + gb[e];
    }
    if (lane == 0) {
        int i1 = 0;
        float v1 = lg[0];
#pragma unroll
        for (int e = 1; e < 6; e++)
            if (lg[e] > v1) { v1 = lg[e]; i1 = e; }
        int i2 = (i1 == 0) ? 1 : 0;
        float v2 = lg[i2];
#pragma unroll
        for (int e = 0; e < 6; e++)
            if (e != i1 && lg[e] > v2) { v2 = lg[e]; i2 = e; }
        float pa = 1.f / (1.f + expf(v2 - v1));
        topi[row * 2] = i1;
        topi[row * 2 + 1] = i2;
        topp[row * 2] = pa;
        topp[row * 2 + 1] = 1.f - pa;
        int s1 = atomicAdd(cnt + i1, 1);
        int s2 = atomicAdd(cnt + i2, 1);
        rowlist[i1 * 2048 + s1] = row;
        rowlist[i2 * 2048 + s2] = row;
        slotp[row * 2] = s1;
        slotp[row * 2 + 1] = s2;
    }
}

// ============ expert GEMM: compacted rows; gather A when rowlist != null ============
__global__ __launch_bounds__(64, 4) void moe_gemm(
    const unsigned short* __restrict__ A, long aStride,
    const unsigned short* __restrict__ Bt, const float* __restrict__ bias,
    unsigned short* __restrict__ C,
    const int* __restrict__ cnt, const int* __restrict__ rowlist) {
    int e = blockIdx.z;
    int ne = cnt[e];
    int m0 = blockIdx.x * 64;
    if (m0 >= ne) return;
    const unsigned short* Ae = A + (long)e * aStride;
    const unsigned short* Be = Bt + (long)e * 262144;
    const float* be = bias + e * 512;
    unsigned short* Ce = C + (long)e * 2048 * 512;
    int lane = threadIdx.x, l16 = lane & 15, quad = lane >> 4;
    int n0 = blockIdx.y * 64;
    int arow[4];
#pragma unroll
    for (int i = 0; i < 4; i++) {
        int slot = m0 + i * 16 + l16;
        arow[i] = rowlist ? ((slot < ne) ? rowlist[e * 2048 + slot] : 0) : slot;
    }
    f32x4 acc[4][4];
#pragma unroll
    for (int i = 0; i < 4; i++)
#pragma unroll
        for (int j = 0; j < 4; j++)
#pragma unroll
            for (int r = 0; r < 4; r++) acc[i][j][r] = 0.f;
#pragma unroll 4
    for (int k0 = 0; k0 < 512; k0 += 32) {
        bf16x8 a[4], b[4];
#pragma unroll
        for (int i = 0; i < 4; i++)
            a[i] = *(const bf16x8*)(Ae + (long)arow[i] * 512 + k0 + quad * 8);
#pragma unroll
        for (int j = 0; j < 4; j++)
            b[j] = *(const bf16x8*)(Be + (long)(n0 + j * 16 + l16) * 512 + k0 + quad * 8);
#pragma unroll
        for (int i = 0; i < 4; i++)
#pragma unroll
            for (int j = 0; j < 4; j++)
                acc[i][j] = __builtin_amdgcn_mfma_f32_16x16x32_bf16(a[i], b[j], acc[i][j], 0, 0, 0);
    }
#pragma unroll
    for (int i = 0; i < 4; i++)
#pragma unroll
        for (int j = 0; j < 4; j++) {
            int col = n0 + j * 16 + l16;
            float bcol = be[col];
#pragma unroll
            for (int r = 0; r < 4; r++) {
                int row = m0 + i * 16 + quad * 4 + r;
                float v = fmaxf(acc[i][j][r] + bcol, 0.f);
                Ce[(long)row * 512 + col] = f2b(v);
            }
        }
}

// ============ combine: wave per row, coalesced, shuffle-reduce ============
__global__ __launch_bounds__(256) void combine_k(
    const unsigned short* __restrict__ h2, const float* __restrict__ w3t,
    const float* __restrict__ b3, const int* __restrict__ topi,
    const float* __restrict__ topp, const int* __restrict__ slotp,
    float* __restrict__ out) {
    int b = blockIdx.x * 4 + (threadIdx.x >> 6);
    int lane = threadIdx.x & 63;
    int e0 = topi[b * 2], e1 = topi[b * 2 + 1];
    float p0 = topp[b * 2], p1 = topp[b * 2 + 1];
    int s0 = slotp[b * 2], s1 = slotp[b * 2 + 1];
    float r[12];
#pragma unroll
    for (int a = 0; a < 12; a++) r[a] = 0.f;
#pragma unroll
    for (int j = 0; j < 2; j++) {
        int e = j ? e1 : e0;
        int s = j ? s1 : s0;
        float p = j ? p1 : p0;
        const unsigned short* hp = h2 + ((long)e * 2048 + s) * 512 + lane * 8;
        bf16x8 hv = *(const bf16x8*)hp;
        float hf[8];
#pragma unroll
        for (int q = 0; q < 8; q++) hf[q] = b2f((unsigned short)hv[q]);
        const float* wb = w3t + e * 6144 + lane * 8;
#pragma unroll
        for (int a = 0; a < 12; a++) {
            float4 w0 = *(const float4*)(wb + a * 512);
            float4 w1 = *(const float4*)(wb + a * 512 + 4);
            float acc = hf[0] * w0.x + hf[1] * w0.y + hf[2] * w0.z + hf[3] * w0.w +
                        hf[4] * w1.x + hf[5] * w1.y + hf[6] * w1.z + hf[7] * w1.w;
            r[a] += p * acc;
        }
    }
#pragma unroll
    for (int a = 0; a < 12; a++)
#pragma unroll
        for (int off = 32; off > 0; off >>= 1) r[a] += __shfl_xor(r[a], off, 64);
    float v = 0.f;
#pragma unroll
    for (int a = 0; a < 12; a++)
        if (lane == a) v = r[a];
    if (lane < 12)
        out[b * 12 + lane] = v + p0 * b3[e0 * 12 + lane] + p1 * b3[e1 * 12 + lane];
}

extern "C" void kernel_launch(void* const* d_in, const int* in_sizes, int n_in,
                              void* d_out, int out_size, void* d_ws, size_t ws_size,
                              hipStream_t stream) {
    const float* x   = (const float*)d_in[0];
    const float* c1w = (const float*)d_in[1];
    const float* c1b = (const float*)d_in[2];
    const float* c2w = (const float*)d_in[3];
    const float* c2b = (const float*)d_in[4];
    const float* c3w = (const float*)d_in[5];
    const float* c3b = (const float*)d_in[6];
    const float* fcw = (const float*)d_in[7];
    const float* fcb = (const float*)d_in[8];
    const float* gw  = (const float*)d_in[9];
    const float* gb  = (const float*)d_in[10];
    const float* ew1 = (const float*)d_in[11];
    const float* eb1 = (const float*)d_in[12];
    const float* ew2 = (const float*)d_in[13];
    const float* eb2 = (const float*)d_in[14];
    const float* ew3 = (const float*)d_in[15];
    const float* eb3 = (const float*)d_in[16];

    char* ws = (char*)d_ws;
    unsigned short* y1hi = (unsigned short*)(ws + 0L);          // 52428800 B
    unsigned short* y1lo = (unsigned short*)(ws + 52428800L);   // 52428800 B
    unsigned short* f3hi = (unsigned short*)(ws + 0L);          // alias (y1 dead after conv2)
    unsigned short* f3lo = (unsigned short*)(ws + 12845056L);   // alias
    // moe routing aux: dead region after conv2 (y1hi tail), written from fc_fin on.
    int*   cnt           = (int*)(ws + 26214400L);              // 32 B
    int*   rowlist       = (int*)(ws + 26214464L);              // 49152 B
    int*   slotp         = (int*)(ws + 26263616L);              // 16384 B
    unsigned short* y2hi = (unsigned short*)(ws + 104857600L);  // 21233664 B
    unsigned short* y2lo = (unsigned short*)(ws + 126091264L);  // 21233664 B
    unsigned short* h1   = (unsigned short*)(ws + 104857600L);  // alias (y2 dead after conv3)
    unsigned short* h2   = (unsigned short*)(ws + 117440512L);  // alias
    float* f             = (float*)(ws + 147324928L);           // 4194304 B
    unsigned short* fb   = (unsigned short*)(ws + 151519232L);  // 2097152 B
    int*   topi          = (int*)(ws + 153616384L);             // 16384 B
    float* topp          = (float*)(ws + 153632768L);           // 16384 B
    unsigned short* w2h  = (unsigned short*)(ws + 153681920L);  // 65536 B
    unsigned short* w2l  = (unsigned short*)(ws + 153747456L);  // 65536 B
    unsigned short* w3h  = (unsigned short*)(ws + 153812992L);  // 73728 B
    unsigned short* w3l  = (unsigned short*)(ws + 153886720L);  // 73728 B
    unsigned short* fcwh = (unsigned short*)(ws + 153960448L);  // 3211264 B
    unsigned short* fcwl = (unsigned short*)(ws + 157171712L);  // 3211264 B
    unsigned short* ew1t = (unsigned short*)(ws + 160382976L);  // 3145728 B
    unsigned short* ew2t = (unsigned short*)(ws + 163528704L);  // 3145728 B
    float* w3t           = (float*)(ws + 166674432L);           // 147456 B
    float* Cp            = (float*)(ws + 166821888L);           // 7*4194304 = 29360128 B
    unsigned short* wb1h = (unsigned short*)(ws + 196182016L);  // 16384 B
    unsigned short* wb1l = (unsigned short*)(ws + 196198400L);  // 16384 B (end 196214784)
    float* out = (float*)d_out;

    hipLaunchKernelGGL(prep_w, dim3(448), dim3(256), 0, stream, c1w, c2w, c3w, ew3,
                       wb1h, wb1l, w2h, w2l, w3h, w3l, w3t);
    hipLaunchKernelGGL(prep_fcw, dim3(49, 8), dim3(256), 0, stream, fcw, fcwh, fcwl);
    hipLaunchKernelGGL(prep_ewT, dim3(16, 16, 12), dim3(32, 8), 0, stream, ew1, ew2, ew1t, ew2t);
    hipLaunchKernelGGL(conv1_k, dim3(6400), dim3(256), 0, stream, x, wb1h, wb1l, c1b, y1hi, y1lo);
    hipLaunchKernelGGL((convm_k<32, 20, 20, 9, 9, 2, 4, 4>), dim3(648), dim3(256), 0, stream,
                       y1hi, y1lo, w2h, w2l, c2b, y2hi, y2lo);
    hipLaunchKernelGGL((convm_k<64, 9, 9, 7, 7, 1, 3, 3>), dim3(392), dim3(256), 0, stream,
                       y2hi, y2lo, w3h, w3l, c3b, f3hi, f3lo);
    hipLaunchKernelGGL(fc_k, dim3(32, 8, 7), dim3(64), 0, stream, f3hi, f3lo, fcwh, fcwl, Cp);
    hipLaunchKernelGGL(fc_fin, dim3(4096), dim3(256), 0, stream, Cp, fcb, f, fb, cnt);
    hipLaunchKernelGGL(gate_k, dim3(512), dim3(256), 0, stream, f, gw, gb, topi, topp,
                       cnt, rowlist, slotp);
    hipLaunchKernelGGL(moe_gemm, dim3(32, 8, 6), dim3(64), 0, stream, fb, 0L, ew1t, eb1, h1,
                       cnt, rowlist);
    hipLaunchKernelGGL(moe_gemm, dim3(32, 8, 6), dim3(64), 0, stream, h1, 1048576L, ew2t, eb2, h2,
                       cnt, (const int*)nullptr);
    hipLaunchKernelGGL(combine_k, dim3(512), dim3(256), 0, stream, h2, w3t, eb3, topi, topp,
                       slotp, out);
}

// Round 4
// 685.900 us; speedup vs baseline: 1.0714x; 1.0116x over previous
//
#include <hip/hip_runtime.h>
#include <hip/hip_bf16.h>
#include <math.h>

typedef __attribute__((ext_vector_type(8))) short bf16x8;
typedef __attribute__((ext_vector_type(4))) float f32x4;

__device__ __forceinline__ float b2f(unsigned short u) {
    unsigned int v = ((unsigned int)u) << 16;
    return __uint_as_float(v);
}
__device__ __forceinline__ unsigned short f2b(float f) {
    __hip_bfloat16 h = __float2bfloat16(f);
    return *reinterpret_cast<unsigned short*>(&h);
}
// truncation split: hi = top 16 bits, lo = RNE(v - hi). residual ~2^-17 |v|
__device__ __forceinline__ void split_trunc(float v, short& h, short& l) {
    unsigned int ui = __float_as_uint(v);
    h = (short)(ui >> 16);
    float hf = __uint_as_float(ui & 0xffff0000u);
    l = (short)f2b(v - hf);
}

// ============ prep (fused): conv/w3 weights | fc weights | expert weights ============
__global__ __launch_bounds__(256) void prep_all(
    const float* __restrict__ w1, const float* __restrict__ w2, const float* __restrict__ w3,
    const float* __restrict__ ew3, const float* __restrict__ fw,
    const float* __restrict__ ew1, const float* __restrict__ ew2,
    unsigned short* __restrict__ wb1h, unsigned short* __restrict__ wb1l,
    unsigned short* __restrict__ w2h, unsigned short* __restrict__ w2l,
    unsigned short* __restrict__ w3h, unsigned short* __restrict__ w3l,
    float* __restrict__ w3t,
    unsigned short* __restrict__ fh, unsigned short* __restrict__ fl,
    unsigned short* __restrict__ t1, unsigned short* __restrict__ t2) {
    __shared__ float lds_f[64 * 65];
    int b = blockIdx.x;
    int t = threadIdx.x;
    if (b < 448) {
        // --- section 1: conv weights + w3 transpose (was prep_w) ---
        int tid = b * 256 + t;
        if (tid < 8192) {
            int k = tid >> 8, r = tid & 255;
            int c = r >> 6, ky = (r >> 3) & 7, kx = r & 7;
            float v = w1[tid];
            unsigned short h = f2b(v);
            int d = ((ky * 2 + (k >> 4)) * 16 + (k & 15)) * 32 + c * 8 + kx;
            wb1h[d] = h;
            wb1l[d] = f2b(v - b2f(h));
        } else if (tid < 8192 + 32768) {
            int i = tid - 8192;
            int n = i >> 9, r = i & 511;
            int c = r >> 4, ky = (r >> 2) & 3, kx = r & 3;
            float v = w2[i];
            unsigned short h = f2b(v);
            int d = ((ky * 4 + kx) * 64 + n) * 32 + c;
            w2h[d] = h;
            w2l[d] = f2b(v - b2f(h));
        } else if (tid < 8192 + 32768 + 36864) {
            int i = tid - 40960;
            int n = i / 576, r = i - n * 576;
            int c = r / 9, s = r - c * 9;
            int ky = s / 3, kx = s - ky * 3;
            float v = w3[i];
            unsigned short h = f2b(v);
            int d = (((ky * 3 + kx) * 2 + (c >> 5)) * 64 + n) * 32 + (c & 31);
            w3h[d] = h;
            w3l[d] = f2b(v - b2f(h));
        } else if (tid < 77824 + 36864) {
            int i = tid - 77824;
            int e = i / 6144, rem = i - e * 6144;
            int a = rem >> 9, k = rem & 511;
            w3t[i] = ew3[e * 6144 + k * 12 + a];
        }
    } else if (b < 840) {
        // --- section 2: fc_w[(c*49+p)*512+n] -> fcw[n][(p*64+c)] hi/lo (was prep_fcw) ---
        int bx = b - 448;
        int k0 = (bx % 49) * 64;
        int n0 = (bx / 49) * 64;
        int tx = t & 63, ty = t >> 6;
#pragma unroll
        for (int j = 0; j < 16; j++) {
            int kk = ty + j * 4;
            int kp = k0 + kk;
            int p = kp >> 6, c = kp & 63;
            lds_f[kk * 65 + tx] = fw[(c * 49 + p) * 512 + n0 + tx];
        }
        __syncthreads();
#pragma unroll
        for (int j = 0; j < 16; j++) {
            int r = ty + j * 4;
            float v = lds_f[tx * 65 + r];
            unsigned short hh = f2b(v);
            long d = (long)(n0 + r) * 3136 + k0 + tx;
            fh[d] = hh;
            fl[d] = f2b(v - b2f(hh));
        }
    } else {
        // --- section 3: expert weights [e][d][h] -> bf16 [e][h][d] (was prep_ewT) ---
        int i = b - 840;
        int h0 = (i & 15) * 32;
        int d0 = ((i >> 4) & 15) * 32;
        int z = i >> 8;
        int e = z % 6;
        const float* src = (z < 6) ? (ew1 + e * 262144) : (ew2 + e * 262144);
        unsigned short* dst = (z < 6) ? (t1 + e * 262144) : (t2 + e * 262144);
        int tx = t & 31, ty = t >> 5;
#pragma unroll
        for (int j = 0; j < 4; j++)
            lds_f[(ty + j * 8) * 33 + tx] = src[(d0 + ty + j * 8) * 512 + h0 + tx];
        __syncthreads();
#pragma unroll
        for (int j = 0; j < 4; j++)
            dst[(h0 + ty + j * 8) * 512 + (d0 + tx)] = f2b(lds_f[tx * 33 + ty + j * 8]);
    }
}

// ============ conv1: direct MFMA. Weights in LDS (lgkmcnt path). x rows in a
// 4-slot register ring, issue pinned 3 rows ahead with sched_barrier(0) so the
// scheduler cannot sink the prefetch. 32 px/wave, 4 waves/SIMD, XCD-swizzled
// blockIdx for input L2 locality. ============
__global__ __launch_bounds__(256, 4) void conv1_k(
    const float* __restrict__ x, const unsigned short* __restrict__ wbh,
    const unsigned short* __restrict__ wbl, const float* __restrict__ b1,
    unsigned short* __restrict__ yhi, unsigned short* __restrict__ ylo) {
    // [ky][table][lane] fragment-major: ds_read_b128 at lane*16 -> conflict-free
    __shared__ bf16x8 wlds[8][4][64];
    int t = threadIdx.x;
    {
        int tab = t >> 6, ln = t & 63;
        const unsigned short* sb = ((tab < 2) ? wbh : wbl) +
            ((ln & 15) * 32 + (ln >> 4) * 8 + (tab & 1) * 512);
#pragma unroll
        for (int k = 0; k < 8; k++)
            wlds[k][tab][ln] = *(const bf16x8*)(sb + k * 1024);
    }
    // bijective XCD swizzle: 6400 blocks = 8 x 800 contiguous chunks
    int swz = (blockIdx.x & 7) * 800 + (blockIdx.x >> 3);
    int wave = t >> 6, lane = t & 63, l16 = lane & 15, quad = lane >> 4;
    int px0 = swz * 128 + wave * 32;
    const float* abase[2];
#pragma unroll
    for (int i = 0; i < 2; i++) {
        int px = px0 + i * 16 + l16;
        int n = px / 400;
        int rem = px - n * 400;
        int oy = rem / 20;
        int ox = rem - oy * 20;
        abase[i] = x + (long)n * 28224 + quad * 7056 + oy * 4 * 84 + ox * 4;
    }
    f32x4 acc[2][2];
#pragma unroll
    for (int i = 0; i < 2; i++)
#pragma unroll
        for (int j = 0; j < 2; j++)
#pragma unroll
            for (int r = 0; r < 4; r++) acc[i][j][r] = 0.f;
    __syncthreads();
    float4 buf[4][4];  // [row&3][frag*2+half] ring; indices compile-time after unroll
    // prologue: issue rows 0..2, pinned
#pragma unroll
    for (int r = 0; r < 3; r++) {
        __builtin_amdgcn_sched_barrier(0);
#pragma unroll
        for (int i = 0; i < 2; i++) {
            const float* p = abase[i] + r * 84;
            buf[r][i * 2] = *(const float4*)p;
            buf[r][i * 2 + 1] = *(const float4*)(p + 4);
        }
        __builtin_amdgcn_sched_barrier(0);
    }
#pragma unroll
    for (int ky = 0; ky < 8; ky++) {
        if (ky < 5) {
            __builtin_amdgcn_sched_barrier(0);
#pragma unroll
            for (int i = 0; i < 2; i++) {
                const float* p = abase[i] + (ky + 3) * 84;
                buf[(ky + 3) & 3][i * 2] = *(const float4*)p;
                buf[(ky + 3) & 3][i * 2 + 1] = *(const float4*)(p + 4);
            }
            __builtin_amdgcn_sched_barrier(0);
        }
        bf16x8 bh0 = wlds[ky][0][lane];
        bf16x8 bh1 = wlds[ky][1][lane];
        bf16x8 bl0 = wlds[ky][2][lane];
        bf16x8 bl1 = wlds[ky][3][lane];
        bf16x8 ah[2], al[2];
#pragma unroll
        for (int i = 0; i < 2; i++) {
            const float4& c0 = buf[ky & 3][i * 2];
            const float4& c1 = buf[ky & 3][i * 2 + 1];
            float v[8] = {c0.x, c0.y, c0.z, c0.w, c1.x, c1.y, c1.z, c1.w};
#pragma unroll
            for (int j = 0; j < 8; j++) {
                short hh, ll;
                split_trunc(v[j], hh, ll);
                ah[i][j] = hh;
                al[i][j] = ll;
            }
        }
#pragma unroll
        for (int i = 0; i < 2; i++) {
            acc[i][0] = __builtin_amdgcn_mfma_f32_16x16x32_bf16(ah[i], bh0, acc[i][0], 0, 0, 0);
            acc[i][0] = __builtin_amdgcn_mfma_f32_16x16x32_bf16(al[i], bh0, acc[i][0], 0, 0, 0);
            acc[i][0] = __builtin_amdgcn_mfma_f32_16x16x32_bf16(ah[i], bl0, acc[i][0], 0, 0, 0);
            acc[i][1] = __builtin_amdgcn_mfma_f32_16x16x32_bf16(ah[i], bh1, acc[i][1], 0, 0, 0);
            acc[i][1] = __builtin_amdgcn_mfma_f32_16x16x32_bf16(al[i], bh1, acc[i][1], 0, 0, 0);
            acc[i][1] = __builtin_amdgcn_mfma_f32_16x16x32_bf16(ah[i], bl1, acc[i][1], 0, 0, 0);
        }
    }
    float bias0 = b1[l16], bias1 = b1[16 + l16];
#pragma unroll
    for (int i = 0; i < 2; i++) {
#pragma unroll
        for (int r = 0; r < 4; r++) {
            long px = px0 + i * 16 + quad * 4 + r;
            long o = px * 32;
            float v0 = fmaxf(acc[i][0][r] + bias0, 0.f);
            float v1 = fmaxf(acc[i][1][r] + bias1, 0.f);
            short h0, l0, h1, l1;
            split_trunc(v0, h0, l0);
            split_trunc(v1, h1, l1);
            yhi[o + l16] = (unsigned short)h0;
            ylo[o + l16] = (unsigned short)l0;
            yhi[o + 16 + l16] = (unsigned short)h1;
            ylo[o + 16 + l16] = (unsigned short)l1;
        }
    }
}

// ============ conv2/3: 4-wave blocks, B double-buffered in LDS (reg-staged,
// write-late), raw barrier with lgkmcnt-only drain: A prefetch for ck+1 stays
// in flight on vmcnt across the barrier. Each wave owns 64 px. ============
template <int C, int IH, int IW, int OH, int OW, int S, int KH, int KW>
__global__ __launch_bounds__(256, 2) void convm_k(
    const unsigned short* __restrict__ xhi, const unsigned short* __restrict__ xlo,
    const unsigned short* __restrict__ whi, const unsigned short* __restrict__ wlo,
    const float* __restrict__ bias,
    unsigned short* __restrict__ yhi, unsigned short* __restrict__ ylo) {
    constexpr int CH = C / 32;
    constexpr int NCHUNK = KH * KW * CH;
    // [buf][hi/lo][kquad][ch][8]: ds_read_b128 spreads 8 words/bank (minimum)
    __shared__ unsigned short Bst[2][2][4][64][8];
    int t = threadIdx.x;
    int wave = t >> 6, lane = t & 63, l16 = lane & 15, quad = lane >> 4;
    int pxbase = blockIdx.x * 256 + wave * 64;
    long xoff[4];
#pragma unroll
    for (int i = 0; i < 4; i++) {
        int px = pxbase + i * 16 + l16;
        int n = px / (OH * OW);
        int rem = px - n * (OH * OW);
        int oy = rem / OW;
        int ox = rem - oy * OW;
        xoff[i] = (((long)n * IH + oy * S) * IW + ox * S) * C + quad * 8;
    }
    f32x4 acc[4][4];
#pragma unroll
    for (int i = 0; i < 4; i++)
#pragma unroll
        for (int j = 0; j < 4; j++)
#pragma unroll
            for (int r = 0; r < 4; r++) acc[i][j][r] = 0.f;
    // prologue: stage B(0), load A(0)
    long wsrc = (long)lane * 32 + wave * 8;
    uint4 sh = *(const uint4*)(whi + wsrc);
    uint4 sl = *(const uint4*)(wlo + wsrc);
    bf16x8 a_h[4], a_l[4];
    {
#pragma unroll
        for (int i = 0; i < 4; i++) {
            a_h[i] = *(const bf16x8*)(xhi + xoff[i]);
            a_l[i] = *(const bf16x8*)(xlo + xoff[i]);
        }
    }
    *(uint4*)&Bst[0][0][wave][lane][0] = sh;
    *(uint4*)&Bst[0][1][wave][lane][0] = sl;
    asm volatile("s_waitcnt lgkmcnt(0)\n\ts_barrier" ::: "memory");
#pragma unroll
    for (int ck = 0; ck < NCHUNK; ck++) {
        const int cur = ck & 1;
        uint4 nsh, nsl;
        bf16x8 na_h[4], na_l[4];
        if (ck + 1 < NCHUNK) {
            long ws = (long)(ck + 1) * 2048 + lane * 32 + wave * 8;
            nsh = *(const uint4*)(whi + ws);
            nsl = *(const uint4*)(wlo + ws);
            int ck1 = ck + 1;
            int kyx = ck1 / CH;
            int ch = ck1 - kyx * CH;
            int ky = kyx / KW, kx = kyx - ky * KW;
            long k1 = ((long)(ky * IW + kx)) * C + ch * 32;
#pragma unroll
            for (int i = 0; i < 4; i++) {
                na_h[i] = *(const bf16x8*)(xhi + xoff[i] + k1);
                na_l[i] = *(const bf16x8*)(xlo + xoff[i] + k1);
            }
        }
        bf16x8 bh[4], bl[4];
#pragma unroll
        for (int j = 0; j < 4; j++) {
            bh[j] = *(const bf16x8*)&Bst[cur][0][quad][j * 16 + l16][0];
            bl[j] = *(const bf16x8*)&Bst[cur][1][quad][j * 16 + l16][0];
        }
#pragma unroll
        for (int i = 0; i < 4; i++)
#pragma unroll
            for (int j = 0; j < 4; j++) {
                acc[i][j] = __builtin_amdgcn_mfma_f32_16x16x32_bf16(a_h[i], bh[j], acc[i][j], 0, 0, 0);
                acc[i][j] = __builtin_amdgcn_mfma_f32_16x16x32_bf16(a_h[i], bl[j], acc[i][j], 0, 0, 0);
                acc[i][j] = __builtin_amdgcn_mfma_f32_16x16x32_bf16(a_l[i], bh[j], acc[i][j], 0, 0, 0);
            }
        if (ck + 1 < NCHUNK) {
            __builtin_amdgcn_sched_barrier(0);
            *(uint4*)&Bst[cur ^ 1][0][wave][lane][0] = nsh;
            *(uint4*)&Bst[cur ^ 1][1][wave][lane][0] = nsl;
            asm volatile("s_waitcnt lgkmcnt(0)\n\ts_barrier" ::: "memory");
#pragma unroll
            for (int i = 0; i < 4; i++) {
                a_h[i] = na_h[i];
                a_l[i] = na_l[i];
            }
        }
    }
#pragma unroll
    for (int i = 0; i < 4; i++)
#pragma unroll
        for (int j = 0; j < 4; j++) {
            int col = j * 16 + l16;
            float bv = bias[col];
#pragma unroll
            for (int r = 0; r < 4; r++) {
                int prow = pxbase + i * 16 + quad * 4 + r;
                float v = fmaxf(acc[i][j][r] + bv, 0.f);
                unsigned short h = f2b(v);
                yhi[(long)prow * 64 + col] = h;
                ylo[(long)prow * 64 + col] = f2b(v - b2f(h));
            }
        }
}

// ============ fc: LDS-free split-bf16 MFMA, 1 wave per block, K-split x7.
// Block (0,0,0) also zeroes the moe routing counters (runs before fin_gate). ============
__global__ __launch_bounds__(64, 3) void fc_k(
    const unsigned short* __restrict__ Ahi, const unsigned short* __restrict__ Alo,
    const unsigned short* __restrict__ Bhi, const unsigned short* __restrict__ Blo,
    float* __restrict__ Cp, int* __restrict__ cnt) {
    if (blockIdx.x == 0 && blockIdx.y == 0 && blockIdx.z == 0 && threadIdx.x < 8)
        cnt[threadIdx.x] = 0;
    int lane = threadIdx.x, l16 = lane & 15, quad = lane >> 4;
    int m0 = blockIdx.x * 64, n0 = blockIdx.y * 64;
    int z = blockIdx.z;
    int kBase = z * 448;
    f32x4 acc[4][4];
#pragma unroll
    for (int i = 0; i < 4; i++)
#pragma unroll
        for (int j = 0; j < 4; j++)
#pragma unroll
            for (int r = 0; r < 4; r++) acc[i][j][r] = 0.f;
#pragma unroll 2
    for (int k0 = kBase; k0 < kBase + 448; k0 += 32) {
        bf16x8 ah[4], al[4], bh[4], bl[4];
#pragma unroll
        for (int i = 0; i < 4; i++) {
            long a = (long)(m0 + i * 16 + l16) * 3136 + k0 + quad * 8;
            ah[i] = *(const bf16x8*)(Ahi + a);
            al[i] = *(const bf16x8*)(Alo + a);
        }
#pragma unroll
        for (int j = 0; j < 4; j++) {
            long b = (long)(n0 + j * 16 + l16) * 3136 + k0 + quad * 8;
            bh[j] = *(const bf16x8*)(Bhi + b);
            bl[j] = *(const bf16x8*)(Blo + b);
        }
#pragma unroll
        for (int i = 0; i < 4; i++)
#pragma unroll
            for (int j = 0; j < 4; j++) {
                acc[i][j] = __builtin_amdgcn_mfma_f32_16x16x32_bf16(ah[i], bh[j], acc[i][j], 0, 0, 0);
                acc[i][j] = __builtin_amdgcn_mfma_f32_16x16x32_bf16(ah[i], bl[j], acc[i][j], 0, 0, 0);
                acc[i][j] = __builtin_amdgcn_mfma_f32_16x16x32_bf16(al[i], bh[j], acc[i][j], 0, 0, 0);
            }
    }
    float* Cz = Cp + (long)z * 1048576;
#pragma unroll
    for (int i = 0; i < 4; i++)
#pragma unroll
        for (int j = 0; j < 4; j++) {
            int col = n0 + j * 16 + l16;
#pragma unroll
            for (int r = 0; r < 4; r++) {
                int row = m0 + i * 16 + quad * 4 + r;
                Cz[row * 512 + col] = acc[i][j][r];
            }
        }
}

// ============ fin_gate (fused): sum 7 partials + bias + relu -> fb + LDS row,
// then top-2 gate + expert-row compaction from the LDS row. One block per row. ============
__global__ __launch_bounds__(256) void fin_gate(
    const float* __restrict__ Cp, const float* __restrict__ bias,
    const float* __restrict__ gw, const float* __restrict__ gb,
    unsigned short* __restrict__ fb, int* __restrict__ topi, float* __restrict__ topp,
    int* __restrict__ cnt, int* __restrict__ rowlist, int* __restrict__ slotp) {
    __shared__ float frow[512];
    int row = blockIdx.x;
    int t = threadIdx.x;
#pragma unroll
    for (int s = 0; s < 2; s++) {
        int c = t + s * 256;
        long base = (long)row * 512 + c;
        float v = bias[c];
#pragma unroll
        for (int z = 0; z < 7; z++) v += Cp[base + (long)z * 1048576];
        v = fmaxf(v, 0.f);
        fb[base] = f2b(v);
        frow[c] = v;
    }
    __syncthreads();
    if (t < 64) {
        int lane = t;
        float fv[8];
#pragma unroll
        for (int j = 0; j < 8; j++) fv[j] = frow[lane + 64 * j];
        float lg[6];
#pragma unroll
        for (int e = 0; e < 6; e++) {
            float a = 0.f;
#pragma unroll
            for (int j = 0; j < 8; j++) a += fv[j] * gw[(lane + 64 * j) * 6 + e];
#pragma unroll
            for (int off = 32; off > 0; off >>= 1) a += __shfl_xor(a, off, 64);
            lg[e] = a + gb[e];
        }
        if (lane == 0) {
            int i1 = 0;
            float v1 = lg[0];
#pragma unroll
            for (int e = 1; e < 6; e++)
                if (lg[e] > v1) { v1 = lg[e]; i1 = e; }
            int i2 = (i1 == 0) ? 1 : 0;
            float v2 = lg[i2];
#pragma unroll
            for (int e = 0; e < 6; e++)
                if (e != i1 && lg[e] > v2) { v2 = lg[e]; i2 = e; }
            float pa = 1.f / (1.f + expf(v2 - v1));
            topi[row * 2] = i1;
            topi[row * 2 + 1] = i2;
            topp[row * 2] = pa;
            topp[row * 2 + 1] = 1.f - pa;
            int s1 = atomicAdd(cnt + i1, 1);
            int s2 = atomicAdd(cnt + i2, 1);
            rowlist[i1 * 2048 + s1] = row;
            rowlist[i2 * 2048 + s2] = row;
            slotp[row * 2] = s1;
            slotp[row * 2 + 1] = s2;
        }
    }
}

// ============ expert GEMM: compacted rows; gather A when rowlist != null ============
__global__ __launch_bounds__(64, 4) void moe_gemm(
    const unsigned short* __restrict__ A, long aStride,
    const unsigned short* __restrict__ Bt, const float* __restrict__ bias,
    unsigned short* __restrict__ C,
    const int* __restrict__ cnt, const int* __restrict__ rowlist) {
    int e = blockIdx.z;
    int ne = cnt[e];
    int m0 = blockIdx.x * 64;
    if (m0 >= ne) return;
    const unsigned short* Ae = A + (long)e * aStride;
    const unsigned short* Be = Bt + (long)e * 262144;
    const float* be = bias + e * 512;
    unsigned short* Ce = C + (long)e * 2048 * 512;
    int lane = threadIdx.x, l16 = lane & 15, quad = lane >> 4;
    int n0 = blockIdx.y * 64;
    int arow[4];
#pragma unroll
    for (int i = 0; i < 4; i++) {
        int slot = m0 + i * 16 + l16;
        arow[i] = rowlist ? ((slot < ne) ? rowlist[e * 2048 + slot] : 0) : slot;
    }
    f32x4 acc[4][4];
#pragma unroll
    for (int i = 0; i < 4; i++)
#pragma unroll
        for (int j = 0; j < 4; j++)
#pragma unroll
            for (int r = 0; r < 4; r++) acc[i][j][r] = 0.f;
#pragma unroll 4
    for (int k0 = 0; k0 < 512; k0 += 32) {
        bf16x8 a[4], b[4];
#pragma unroll
        for (int i = 0; i < 4; i++)
            a[i] = *(const bf16x8*)(Ae + (long)arow[i] * 512 + k0 + quad * 8);
#pragma unroll
        for (int j = 0; j < 4; j++)
            b[j] = *(const bf16x8*)(Be + (long)(n0 + j * 16 + l16) * 512 + k0 + quad * 8);
#pragma unroll
        for (int i = 0; i < 4; i++)
#pragma unroll
            for (int j = 0; j < 4; j++)
                acc[i][j] = __builtin_amdgcn_mfma_f32_16x16x32_bf16(a[i], b[j], acc[i][j], 0, 0, 0);
    }
#pragma unroll
    for (int i = 0; i < 4; i++)
#pragma unroll
        for (int j = 0; j < 4; j++) {
            int col = n0 + j * 16 + l16;
            float bcol = be[col];
#pragma unroll
            for (int r = 0; r < 4; r++) {
                int row = m0 + i * 16 + quad * 4 + r;
                float v = fmaxf(acc[i][j][r] + bcol, 0.f);
                Ce[(long)row * 512 + col] = f2b(v);
            }
        }
}

// ============ combine: wave per row, coalesced, shuffle-reduce ============
__global__ __launch_bounds__(256) void combine_k(
    const unsigned short* __restrict__ h2, const float* __restrict__ w3t,
    const float* __restrict__ b3, const int* __restrict__ topi,
    const float* __restrict__ topp, const int* __restrict__ slotp,
    float* __restrict__ out) {
    int b = blockIdx.x * 4 + (threadIdx.x >> 6);
    int lane = threadIdx.x & 63;
    int e0 = topi[b * 2], e1 = topi[b * 2 + 1];
    float p0 = topp[b * 2], p1 = topp[b * 2 + 1];
    int s0 = slotp[b * 2], s1 = slotp[b * 2 + 1];
    float r[12];
#pragma unroll
    for (int a = 0; a < 12; a++) r[a] = 0.f;
#pragma unroll
    for (int j = 0; j < 2; j++) {
        int e = j ? e1 : e0;
        int s = j ? s1 : s0;
        float p = j ? p1 : p0;
        const unsigned short* hp = h2 + ((long)e * 2048 + s) * 512 + lane * 8;
        bf16x8 hv = *(const bf16x8*)hp;
        float hf[8];
#pragma unroll
        for (int q = 0; q < 8; q++) hf[q] = b2f((unsigned short)hv[q]);
        const float* wb = w3t + e * 6144 + lane * 8;
#pragma unroll
        for (int a = 0; a < 12; a++) {
            float4 w0 = *(const float4*)(wb + a * 512);
            float4 w1 = *(const float4*)(wb + a * 512 + 4);
            float acc = hf[0] * w0.x + hf[1] * w0.y + hf[2] * w0.z + hf[3] * w0.w +
                        hf[4] * w1.x + hf[5] * w1.y + hf[6] * w1.z + hf[7] * w1.w;
            r[a] += p * acc;
        }
    }
#pragma unroll
    for (int a = 0; a < 12; a++)
#pragma unroll
        for (int off = 32; off > 0; off >>= 1) r[a] += __shfl_xor(r[a], off, 64);
    float v = 0.f;
#pragma unroll
    for (int a = 0; a < 12; a++)
        if (lane == a) v = r[a];
    if (lane < 12)
        out[b * 12 + lane] = v + p0 * b3[e0 * 12 + lane] + p1 * b3[e1 * 12 + lane];
}

extern "C" void kernel_launch(void* const* d_in, const int* in_sizes, int n_in,
                              void* d_out, int out_size, void* d_ws, size_t ws_size,
                              hipStream_t stream) {
    const float* x   = (const float*)d_in[0];
    const float* c1w = (const float*)d_in[1];
    const float* c1b = (const float*)d_in[2];
    const float* c2w = (const float*)d_in[3];
    const float* c2b = (const float*)d_in[4];
    const float* c3w = (const float*)d_in[5];
    const float* c3b = (const float*)d_in[6];
    const float* fcw = (const float*)d_in[7];
    const float* fcb = (const float*)d_in[8];
    const float* gw  = (const float*)d_in[9];
    const float* gb  = (const float*)d_in[10];
    const float* ew1 = (const float*)d_in[11];
    const float* eb1 = (const float*)d_in[12];
    const float* ew2 = (const float*)d_in[13];
    const float* eb2 = (const float*)d_in[14];
    const float* ew3 = (const float*)d_in[15];
    const float* eb3 = (const float*)d_in[16];

    char* ws = (char*)d_ws;
    unsigned short* y1hi = (unsigned short*)(ws + 0L);          // 52428800 B
    unsigned short* y1lo = (unsigned short*)(ws + 52428800L);   // 52428800 B
    unsigned short* f3hi = (unsigned short*)(ws + 0L);          // alias (y1 dead after conv2)
    unsigned short* f3lo = (unsigned short*)(ws + 12845056L);   // alias
    // moe routing aux: dead region after conv2 (y1hi tail), written from fc_k on.
    int*   cnt           = (int*)(ws + 26214400L);              // 32 B
    int*   rowlist       = (int*)(ws + 26214464L);              // 49152 B
    int*   slotp         = (int*)(ws + 26263616L);              // 16384 B
    unsigned short* y2hi = (unsigned short*)(ws + 104857600L);  // 21233664 B
    unsigned short* y2lo = (unsigned short*)(ws + 126091264L);  // 21233664 B
    unsigned short* h1   = (unsigned short*)(ws + 104857600L);  // alias (y2 dead after conv3)
    unsigned short* h2   = (unsigned short*)(ws + 117440512L);  // alias
    unsigned short* fb   = (unsigned short*)(ws + 151519232L);  // 2097152 B
    int*   topi          = (int*)(ws + 153616384L);             // 16384 B
    float* topp          = (float*)(ws + 153632768L);           // 16384 B
    unsigned short* w2h  = (unsigned short*)(ws + 153681920L);  // 65536 B
    unsigned short* w2l  = (unsigned short*)(ws + 153747456L);  // 65536 B
    unsigned short* w3h  = (unsigned short*)(ws + 153812992L);  // 73728 B
    unsigned short* w3l  = (unsigned short*)(ws + 153886720L);  // 73728 B
    unsigned short* fcwh = (unsigned short*)(ws + 153960448L);  // 3211264 B
    unsigned short* fcwl = (unsigned short*)(ws + 157171712L);  // 3211264 B
    unsigned short* ew1t = (unsigned short*)(ws + 160382976L);  // 3145728 B
    unsigned short* ew2t = (unsigned short*)(ws + 163528704L);  // 3145728 B
    float* w3t           = (float*)(ws + 166674432L);           // 147456 B
    float* Cp            = (float*)(ws + 166821888L);           // 7*4194304 = 29360128 B
    unsigned short* wb1h = (unsigned short*)(ws + 196182016L);  // 16384 B
    unsigned short* wb1l = (unsigned short*)(ws + 196198400L);  // 16384 B (end 196214784)
    float* out = (float*)d_out;

    hipLaunchKernelGGL(prep_all, dim3(3912), dim3(256), 0, stream,
                       c1w, c2w, c3w, ew3, fcw, ew1, ew2,
                       wb1h, wb1l, w2h, w2l, w3h, w3l, w3t, fcwh, fcwl, ew1t, ew2t);
    hipLaunchKernelGGL(conv1_k, dim3(6400), dim3(256), 0, stream, x, wb1h, wb1l, c1b, y1hi, y1lo);
    hipLaunchKernelGGL((convm_k<32, 20, 20, 9, 9, 2, 4, 4>), dim3(648), dim3(256), 0, stream,
                       y1hi, y1lo, w2h, w2l, c2b, y2hi, y2lo);
    hipLaunchKernelGGL((convm_k<64, 9, 9, 7, 7, 1, 3, 3>), dim3(392), dim3(256), 0, stream,
                       y2hi, y2lo, w3h, w3l, c3b, f3hi, f3lo);
    hipLaunchKernelGGL(fc_k, dim3(32, 8, 7), dim3(64), 0, stream, f3hi, f3lo, fcwh, fcwl, Cp, cnt);
    hipLaunchKernelGGL(fin_gate, dim3(2048), dim3(256), 0, stream, Cp, fcb, gw, gb,
                       fb, topi, topp, cnt, rowlist, slotp);
    hipLaunchKernelGGL(moe_gemm, dim3(32, 8, 6), dim3(64), 0, stream, fb, 0L, ew1t, eb1, h1,
                       cnt, rowlist);
    hipLaunchKernelGGL(moe_gemm, dim3(32, 8, 6), dim3(64), 0, stream, h1, 1048576L, ew2t, eb2, h2,
                       cnt, (const int*)nullptr);
    hipLaunchKernelGGL(combine_k, dim3(512), dim3(256), 0, stream, h2, w3t, eb3, topi, topp,
                       slotp, out);
}